// Round 17
// baseline (1176.064 us; speedup 1.0000x reference)
//
#include <hip/hip_runtime.h>
#include <cstdint>

typedef __bf16 bf16_t;
typedef __bf16 bf16x2 __attribute__((ext_vector_type(2)));
typedef __bf16 bf16x4 __attribute__((ext_vector_type(4)));
typedef __bf16 bf16x8 __attribute__((ext_vector_type(8)));
typedef float f32x4 __attribute__((ext_vector_type(4)));
typedef unsigned short u16;
typedef unsigned int u32;
typedef unsigned short u16x8 __attribute__((ext_vector_type(8)));

#define DEVI static __device__ __forceinline__

// async global->LDS, 16B per lane; LDS dest = wave-uniform base + lane*16
DEVI void g2l16(const void* g, void* l) {
  __builtin_amdgcn_global_load_lds((__attribute__((address_space(1))) void*)g,
                                   (__attribute__((address_space(3))) void*)l,
                                   16, 0, 0);
}

// sorted-desc top-4 insert of packed u32 keys
DEVI void tki4(u32* k, u32 nk) {
  if (nk <= k[3]) return;
  k[3] = nk;
  if (k[3] > k[2]) { u32 t = k[2]; k[2] = k[3]; k[3] = t; }
  if (k[2] > k[1]) { u32 t = k[1]; k[1] = k[2]; k[2] = t; }
  if (k[1] > k[0]) { u32 t = k[0]; k[0] = k[1]; k[1] = t; }
}

// ---------------- fused f32->bf16 convert + embedding (one launch) ----------------
struct F2BArgs {
  const float* s[10];
  bf16_t* d[10];
  int n4[10];
  const int* ids;
  const float* pos;
  float* x;
  bf16_t* xb;
};
__global__ void k_f2b_all(F2BArgs a) {
  const int seg = blockIdx.y;
  if (seg == 10) {
    const int d = threadIdx.x * 2;
    for (int r = blockIdx.x; r < 4096; r += gridDim.x) {
      const int t = r & 2047;
      const long id = a.ids[r];
      float2 av = *(const float2*)(a.s[0] + id * 512 + d);
      float2 p = *(const float2*)(a.pos + (long)t * 512 + d);
      float o0 = av.x + p.x, o1 = av.y + p.y;
      *(float2*)(a.x + (long)r * 512 + d) = make_float2(o0, o1);
      bf16x2 ob = {(bf16_t)o0, (bf16_t)o1};
      *(bf16x2*)(a.xb + (long)r * 512 + d) = ob;
    }
    return;
  }
  const float* __restrict__ in = a.s[seg];
  bf16_t* __restrict__ out = a.d[seg];
  const long n4 = a.n4[seg];
  const long stride = (long)gridDim.x * blockDim.x;
  for (long i = (long)blockIdx.x * blockDim.x + threadIdx.x; i < n4; i += stride) {
    float4 v = ((const float4*)in)[i];
    bf16x4 o = {(bf16_t)v.x, (bf16_t)v.y, (bf16_t)v.z, (bf16_t)v.w};
    ((bf16x4*)out)[i] = o;
  }
}

DEVI float gelu_f(float f) {
  return 0.5f * f * (1.0f + erff(f * 0.70710678118654752f));
}

// ---------------- 128x128 GEMM, 4-slot counted-vmcnt pipeline ----------------
// Used only for score (EPI=3) and lm_head (EPI=0) -> XCD-chunked m-fastest block
// swizzle: each XCD's concurrent blocks share B panels + A fully L2-resident.
// EPI: 0 plain store; 2 gelu->bf16; 3 score top-4 -> cand[M][224][4].
template <typename CT, bool BIAS, int EPI>
__global__ __launch_bounds__(256, 2) void k_gemm_bt(
    const bf16_t* __restrict__ A, int lda, const bf16_t* __restrict__ B, int ldb,
    CT* __restrict__ C, int ldc, const float* __restrict__ bias, int K, float alpha,
    const float* __restrict__ s0, const float* __restrict__ s1,
    const float* __restrict__ s2, u32* __restrict__ cand) {
  __shared__ bf16_t As[4][4096];  // slot x [128][32]
  __shared__ bf16_t Bs[4][4096];
  const int tid = threadIdx.x;
  const int lane = tid & 63;
  const int w = tid >> 6;
  const int wm = w >> 1, wn = w & 1;
  // XCD-bijective chunked swizzle, m-fastest (requires nwg % 8 == 0)
  const int nwg = gridDim.x * gridDim.y;
  const int orig = blockIdx.y * gridDim.x + blockIdx.x;
  const int g = ((nwg & 7) == 0) ? ((orig & 7) * (nwg >> 3) + (orig >> 3)) : orig;
  const int m0 = (g % gridDim.y) * 128;
  const int n0 = (g / gridDim.y) * 128;

  f32x4 acc[4][4];
#pragma unroll
  for (int m = 0; m < 4; ++m)
#pragma unroll
    for (int n = 0; n < 4; ++n) acc[m][n] = (f32x4){0.f, 0.f, 0.f, 0.f};

  const int srow = tid >> 2;
  const int scol = ((tid & 3) ^ ((srow >> 1) & 3)) * 8;  // pre-swizzled source granule
  const int fr = lane & 15;
  const int g4 = lane >> 4;
  const int kg = g4 * 8;
  const int NT = K >> 5;

  auto stage = [&](int kp) {
    const int slot = kp & 3;
    bf16_t* as = As[slot];
    bf16_t* bs = Bs[slot];
    const int k0 = kp * 32;
    g2l16(A + (long long)(m0 + srow) * lda + (k0 + scol), as + tid * 8);
    g2l16(A + (long long)(m0 + 64 + srow) * lda + (k0 + scol), as + 2048 + tid * 8);
    g2l16(B + (long long)(n0 + srow) * ldb + (k0 + scol), bs + tid * 8);
    g2l16(B + (long long)(n0 + 64 + srow) * ldb + (k0 + scol), bs + 2048 + tid * 8);
  };

  stage(0);
  stage(1);
  asm volatile("s_waitcnt vmcnt(4)" ::: "memory");
  __builtin_amdgcn_s_barrier();
  __builtin_amdgcn_sched_barrier(0);

  for (int k = 0; k < NT; ++k) {
    const int slot = k & 3;
    const bf16_t* as = As[slot];
    const bf16_t* bs = Bs[slot];
    bf16x8 fa[4], fb[4];
#pragma unroll
    for (int m = 0; m < 4; ++m) {
      const int row = wm * 64 + m * 16 + fr;
      fa[m] = *(const bf16x8*)(as + row * 32 + (kg ^ (((row >> 1) & 3) << 3)));
    }
#pragma unroll
    for (int n = 0; n < 4; ++n) {
      const int row = wn * 64 + n * 16 + fr;
      fb[n] = *(const bf16x8*)(bs + row * 32 + (kg ^ (((row >> 1) & 3) << 3)));
    }
    if (k + 2 < NT) stage(k + 2);
    if (k < NT - 2) {
      asm volatile("s_waitcnt vmcnt(4)" ::: "memory");
    } else {
      asm volatile("s_waitcnt vmcnt(0)" ::: "memory");
    }
    __builtin_amdgcn_s_barrier();
    __builtin_amdgcn_sched_barrier(0);
    __builtin_amdgcn_s_setprio(1);
#pragma unroll
    for (int m = 0; m < 4; ++m)
#pragma unroll
      for (int n = 0; n < 4; ++n)
        acc[m][n] = __builtin_amdgcn_mfma_f32_16x16x32_bf16(fa[m], fb[n], acc[m][n], 0, 0, 0);
    __builtin_amdgcn_s_setprio(0);
  }

  if (EPI == 3) {
    // ---- score epilogue: add salience, block-local per-row top-4 -> cand ----
    const float* salp;
    if (n0 < 16384) salp = s0 + n0;
    else if (n0 < 24576) salp = s1 + (n0 - 16384);
    else salp = s2 + (n0 - 24576);
    float bv[4];
    int coll[4];
#pragma unroll
    for (int n = 0; n < 4; ++n) {
      coll[n] = wn * 64 + n * 16 + fr;
      bv[n] = salp[coll[n]];
    }
    __syncthreads();
    u16* slab = (u16*)&As[0][0];  // [128 rows][128 cols] bf16, col idx XOR (row&7)<<3
#pragma unroll
    for (int m = 0; m < 4; ++m) {
#pragma unroll
      for (int r = 0; r < 4; ++r) {
        const int rl = wm * 64 + m * 16 + g4 * 4 + r;
        const int sw = (rl & 7) << 3;
#pragma unroll
        for (int n = 0; n < 4; ++n) {
          bf16_t bvv = (bf16_t)(acc[m][n][r] + bv[n]);
          slab[rl * 128 + (coll[n] ^ sw)] = __builtin_bit_cast(u16, bvv);
        }
      }
    }
    __syncthreads();
    const int rr = tid & 127;
    const int hh = tid >> 7;
    const int sw = (rr & 7) << 3;
    u32 rk[4] = {0u, 0u, 0u, 0u};
    const u32 ibase = 0x7FFFu - (u32)n0;
    u32* res = (u32*)&Bs[0][0];
#pragma unroll
    for (int j = 0; j < 8; ++j) {
      const int c0 = hh * 64 + j * 8;
      u16x8 vv = *(const u16x8*)(slab + rr * 128 + (c0 ^ sw));
#pragma unroll
      for (int e = 0; e < 8; ++e) {
        u16 sb = vv[e];
        u32 k16 = (u32)sb ^ (0x8000u | (0x7FFFu * (u32)(sb >> 15)));
        tki4(rk, (k16 << 15) | (ibase - (u32)(c0 + e)));
      }
    }
#pragma unroll
    for (int j = 0; j < 4; ++j) res[(rr * 2 + hh) * 4 + j] = rk[j];
    __syncthreads();
    if (tid < 128) {
      const u32* rp = res + tid * 8;
      u32 fin[4] = {rp[0], rp[1], rp[2], rp[3]};
      tki4(fin, rp[4]); tki4(fin, rp[5]); tki4(fin, rp[6]); tki4(fin, rp[7]);
      u32* cp = cand + ((long long)(m0 + tid) * 224 + (n0 >> 7)) * 4;
#pragma unroll
      for (int j = 0; j < 4; ++j) cp[j] = fin[j];
    }
    return;
  }

#pragma unroll
  for (int n = 0; n < 4; ++n) {
    const int col = n0 + wn * 64 + n * 16 + fr;
    const float bv = BIAS ? bias[col] : 0.0f;
#pragma unroll
    for (int m = 0; m < 4; ++m) {
      const long long rb = m0 + wm * 64 + m * 16 + g4 * 4;
#pragma unroll
      for (int r = 0; r < 4; ++r) {
        float v = (acc[m][n][r] + bv) * alpha;
        if (EPI == 2) v = gelu_f(v);
        C[(rb + r) * (long long)ldc + col] = (CT)v;
      }
    }
  }
}

// ---------------- 64x128 GEMM, K-split over z, 3-slot counted-vmcnt pipeline ----------------
// EPI: 0 plain store; 1 qkv split (q*0.125->qh, k->kh, v->vt); 2 gelu->bf16.
template <typename CT, bool BIAS, int EPI = 0>
__global__ __launch_bounds__(256, 4) void k_gemm64(
    const bf16_t* __restrict__ A, int lda, const bf16_t* __restrict__ B, int ldb,
    CT* __restrict__ C, int ldc, long long sCz, const float* __restrict__ bias,
    int K, float alpha, bf16_t* __restrict__ qh, bf16_t* __restrict__ kh,
    bf16_t* __restrict__ vt) {
  __shared__ bf16_t As[3][2048];  // slot x [64][32]
  __shared__ bf16_t Bs[3][4096];  // slot x [128][32]
  const int tid = threadIdx.x;
  const int lane = tid & 63;
  const int w = tid >> 6;
  const int wm = w >> 1, wn = w & 1;
  const int m0 = blockIdx.y * 64;
  const int n0 = blockIdx.x * 128;
  const int kz = blockIdx.z;
  A += (long long)kz * K;
  B += (long long)kz * K;
  C += (long long)kz * sCz;

  f32x4 acc[2][4];
#pragma unroll
  for (int m = 0; m < 2; ++m)
#pragma unroll
    for (int n = 0; n < 4; ++n) acc[m][n] = (f32x4){0.f, 0.f, 0.f, 0.f};

  const int srow = tid >> 2;
  const int scol = ((tid & 3) ^ ((srow >> 1) & 3)) * 8;  // pre-swizzled source granule
  const int fr = lane & 15;
  const int g4 = lane >> 4;
  const int kg = g4 * 8;
  const int NT = K >> 5;

  auto stage = [&](int kp) {
    const int slot = kp % 3;
    bf16_t* as = As[slot];
    bf16_t* bs = Bs[slot];
    const int k0 = kp * 32;
    g2l16(A + (long long)(m0 + srow) * lda + (k0 + scol), as + tid * 8);
    g2l16(B + (long long)(n0 + srow) * ldb + (k0 + scol), bs + tid * 8);
    g2l16(B + (long long)(n0 + 64 + srow) * ldb + (k0 + scol), bs + 2048 + tid * 8);
  };

  stage(0);
  stage(1);
  asm volatile("s_waitcnt vmcnt(3)" ::: "memory");
  __builtin_amdgcn_s_barrier();
  __builtin_amdgcn_sched_barrier(0);

  for (int k = 0; k < NT; ++k) {
    const int slot = k % 3;
    const bf16_t* as = As[slot];
    const bf16_t* bs = Bs[slot];
    bf16x8 fa[2], fb[4];
#pragma unroll
    for (int m = 0; m < 2; ++m) {
      const int row = wm * 32 + m * 16 + fr;
      fa[m] = *(const bf16x8*)(as + row * 32 + (kg ^ (((row >> 1) & 3) << 3)));
    }
#pragma unroll
    for (int n = 0; n < 4; ++n) {
      const int row = wn * 64 + n * 16 + fr;
      fb[n] = *(const bf16x8*)(bs + row * 32 + (kg ^ (((row >> 1) & 3) << 3)));
    }
    if (k + 2 < NT) stage(k + 2);
    if (k < NT - 2) {
      asm volatile("s_waitcnt vmcnt(3)" ::: "memory");
    } else {
      asm volatile("s_waitcnt vmcnt(0)" ::: "memory");
    }
    __builtin_amdgcn_s_barrier();
    __builtin_amdgcn_sched_barrier(0);
    __builtin_amdgcn_s_setprio(1);
#pragma unroll
    for (int m = 0; m < 2; ++m)
#pragma unroll
      for (int n = 0; n < 4; ++n)
        acc[m][n] = __builtin_amdgcn_mfma_f32_16x16x32_bf16(fa[m], fb[n], acc[m][n], 0, 0, 0);
    __builtin_amdgcn_s_setprio(0);
  }

#pragma unroll
  for (int n = 0; n < 4; ++n) {
    const int col = n0 + wn * 64 + n * 16 + fr;
    const float bv = (BIAS && kz == 0) ? bias[col] : 0.0f;
    if (EPI == 1) {
      const int reg = col >> 9;
      const int h = (col >> 6) & 7;
      const int hd = col & 63;
#pragma unroll
      for (int m = 0; m < 2; ++m) {
        const int rb = m0 + wm * 32 + m * 16 + g4 * 4;
#pragma unroll
        for (int r = 0; r < 4; ++r) {
          const int row = rb + r;
          const int b = row >> 11, t = row & 2047;
          const long long bh = (long long)b * 8 + h;
          float v = acc[m][n][r] + bv;
          if (reg == 0) qh[(bh * 2048 + t) * 64 + hd] = (bf16_t)(v * 0.125f);
          else if (reg == 1) kh[(bh * 2048 + t) * 64 + hd] = (bf16_t)v;
          else vt[(bh * 64 + hd) * 2048 + t] = (bf16_t)v;
        }
      }
    } else {
#pragma unroll
      for (int m = 0; m < 2; ++m) {
        const long long rb = m0 + wm * 32 + m * 16 + g4 * 4;
#pragma unroll
        for (int r = 0; r < 4; ++r) {
          float v = (acc[m][n][r] + bv) * alpha;
          if (EPI == 2) v = gelu_f(v);
          C[(rb + r) * (long long)ldc + col] = (CT)v;
        }
      }
    }
  }
}

// ---------------- fused flash attention (QBLK=64, KVBLK=128, 512 blocks = 2/CU) ----------------
__global__ __launch_bounds__(256, 2) void k_flash(
    const bf16_t* __restrict__ qh, const bf16_t* __restrict__ kh,
    const bf16_t* __restrict__ vt, bf16_t* __restrict__ out) {
  __shared__ bf16_t Ks[2][128 * 64];
  __shared__ bf16_t Vs[2][64 * 128];
  __shared__ bf16_t Ps[4 * 16 * 128];
  const int tid = threadIdx.x;
  const int lane = tid & 63;
  const int w = tid >> 6;
  const int bh = blockIdx.y;
  const int q0 = blockIdx.x * 64;
  const int fr = lane & 15;
  const int g4 = lane >> 4;
  const int kg = g4 * 8;

  bf16x8 qf[2];
  {
    const bf16_t* qb = qh + ((long long)bh * 2048 + q0 + w * 16) * 64;
#pragma unroll
    for (int ks = 0; ks < 2; ++ks)
      qf[ks] = *(const bf16x8*)(qb + fr * 64 + ks * 32 + kg);
  }

  f32x4 oacc[4];
#pragma unroll
  for (int n = 0; n < 4; ++n) oacc[n] = (f32x4){0.f, 0.f, 0.f, 0.f};
  float li[4] = {0.f, 0.f, 0.f, 0.f};

  char* PsW = (char*)(Ps + w * 16 * 128);
  const bf16_t* kbase = kh + (long long)bh * 2048 * 64;
  const bf16_t* vbase = vt + (long long)bh * 64 * 2048;

  auto stage = [&](int kt, int buf) {
#pragma unroll
    for (int i = 0; i < 4; ++i) {
      int row = (w * 4 + i) * 8 + (lane >> 3);
      int c = lane & 7;
      g2l16(kbase + ((long long)(kt * 128 + row)) * 64 + (c ^ (row & 7)) * 8,
            Ks[buf] + (w * 4 + i) * 512);
      int d = w * 16 + i * 4 + (lane >> 4);
      int c2 = lane & 15;
      g2l16(vbase + (long long)d * 2048 + kt * 128 + ((c2 ^ (d & 7)) * 8),
            Vs[buf] + (w * 16 + i * 4) * 128);
    }
  };

  stage(0, 0);
  int buf = 0;
  for (int kt = 0; kt < 16; ++kt) {
    __syncthreads();
    if (kt + 1 < 16) stage(kt + 1, buf ^ 1);

    f32x4 s[8];
#pragma unroll
    for (int n = 0; n < 8; ++n) s[n] = (f32x4){0.f, 0.f, 0.f, 0.f};
#pragma unroll
    for (int ks = 0; ks < 2; ++ks) {
#pragma unroll
      for (int n = 0; n < 8; ++n) {
        int row = n * 16 + fr;
        bf16x8 kf = *(const bf16x8*)((const char*)Ks[buf] + row * 128 +
                                     ((ks * 64 + kg * 2) ^ ((row & 7) << 4)));
        s[n] = __builtin_amdgcn_mfma_f32_16x16x32_bf16(qf[ks], kf, s[n], 0, 0, 0);
      }
    }

#pragma unroll
    for (int r = 0; r < 4; ++r) {
      const int lr = g4 * 4 + r;
      const int sw = (lr & 7) << 4;
      float rs = 0.f;
#pragma unroll
      for (int n = 0; n < 8; ++n) {
        float p = __expf(s[n][r]);
        rs += p;
        *(bf16_t*)(PsW + lr * 256 + (((n * 16 + fr) * 2) ^ sw)) = (bf16_t)p;
      }
      li[r] += rs;
    }

#pragma unroll
    for (int ks = 0; ks < 4; ++ks) {
      bf16x8 pa = *(const bf16x8*)(PsW + fr * 256 +
                                   ((ks * 64 + kg * 2) ^ ((fr & 7) << 4)));
#pragma unroll
      for (int n = 0; n < 4; ++n) {
        int d = n * 16 + fr;
        bf16x8 vf = *(const bf16x8*)((const char*)Vs[buf] + d * 256 +
                                     ((ks * 64 + kg * 2) ^ ((d & 7) << 4)));
        oacc[n] = __builtin_amdgcn_mfma_f32_16x16x32_bf16(pa, vf, oacc[n], 0, 0, 0);
      }
    }
    buf ^= 1;
  }

#pragma unroll
  for (int r = 0; r < 4; ++r) {
    li[r] += __shfl_xor(li[r], 1);
    li[r] += __shfl_xor(li[r], 2);
    li[r] += __shfl_xor(li[r], 4);
    li[r] += __shfl_xor(li[r], 8);
  }

  const int b = bh >> 3, h = bh & 7;
  bf16_t* ob = out + ((long long)b * 2048 + q0 + w * 16) * 512 + h * 64;
#pragma unroll
  for (int r = 0; r < 4; ++r) {
    float inv = 1.0f / li[r];
#pragma unroll
    for (int n = 0; n < 4; ++n)
      ob[(g4 * 4 + r) * 512 + n * 16 + fr] = (bf16_t)(oacc[n][r] * inv);
  }
}

// ---------------- LN(xin + d1 + d2) * s + b -> xout (f32) + xbf (bf16), D=512 ----------------
// d1/d2 are bf16 K-split partials.
__global__ void k_ln2(const float* __restrict__ xin, const bf16_t* __restrict__ d1,
                      const bf16_t* __restrict__ d2, const float* __restrict__ s,
                      const float* __restrict__ b, float* __restrict__ xout,
                      bf16_t* __restrict__ xbf) {
  __shared__ float red[8];
  const int r = blockIdx.x;
  const int tid = threadIdx.x;
  const int d = tid * 2;
  const int lane = tid & 63, w = tid >> 6;
  float2 xi = *(const float2*)(xin + (long)r * 512 + d);
  bf16x2 e1 = *(const bf16x2*)(d1 + (long)r * 512 + d);
  bf16x2 e2 = *(const bf16x2*)(d2 + (long)r * 512 + d);
  float y0 = xi.x + (float)e1[0] + (float)e2[0];
  float y1 = xi.y + (float)e1[1] + (float)e2[1];
  float sum = y0 + y1, ss = y0 * y0 + y1 * y1;
#pragma unroll
  for (int o = 32; o > 0; o >>= 1) { sum += __shfl_xor(sum, o); ss += __shfl_xor(ss, o); }
  if (lane == 0) { red[w] = sum; red[4 + w] = ss; }
  __syncthreads();
  sum = red[0] + red[1] + red[2] + red[3];
  ss = red[4] + red[5] + red[6] + red[7];
  const float mean = sum * (1.0f / 512.0f);
  const float var = ss * (1.0f / 512.0f) - mean * mean;
  const float rstd = rsqrtf(var + 1e-5f);
  float o0 = (y0 - mean) * rstd * s[d] + b[d];
  float o1 = (y1 - mean) * rstd * s[d + 1] + b[d + 1];
  if (xout) *(float2*)(xout + (long)r * 512 + d) = make_float2(o0, o1);
  bf16x2 ob = {(bf16_t)o0, (bf16_t)o1};
  *(bf16x2*)(xbf + (long)r * 512 + d) = ob;
}

// ---------------- fused: merge candidates (waves 0-2, one level each) + gather V ----------------
__global__ void k_topkread(const u32* __restrict__ cand, const float* __restrict__ V0,
                           const float* __restrict__ V1, const float* __restrict__ V2,
                           bf16_t* __restrict__ readb) {
  __shared__ float tvS[3][4];
  __shared__ int tiS[3][4];
  const int r = blockIdx.x;
  const int lane = threadIdx.x & 63;
  const int w = threadIdx.x >> 6;
  if (w < 3) {
    const int cnt = w == 0 ? 128 : (w == 1 ? 64 : 32);
    const int base = w == 0 ? 0 : (w == 1 ? 128 : 192);
    const int coff = w == 0 ? 0 : (w == 1 ? 16384 : 24576);
    const u32* cr = cand + (long long)r * 224 + base;
    u32 rk[4] = {0u, 0u, 0u, 0u};
    for (int j = lane; j < cnt; j += 64) tki4(rk, cr[j]);
#pragma unroll
    for (int dd = 1; dd < 64; dd <<= 1) {
      u32 o[4];
#pragma unroll
      for (int j = 0; j < 4; ++j) o[j] = (u32)__shfl_xor((int)rk[j], dd);
#pragma unroll
      for (int j = 0; j < 4; ++j) tki4(rk, o[j]);
    }
    if (lane == 0) {
#pragma unroll
      for (int j = 0; j < 4; ++j) {
        u32 k16 = rk[j] >> 15;
        u16 b = (k16 & 0x8000u) ? (u16)(k16 ^ 0x8000u) : (u16)(~k16);
        u32 fb = ((u32)b) << 16;
        tvS[w][j] = __uint_as_float(fb);
        tiS[w][j] = (0x7FFF - (int)(rk[j] & 0x7FFF)) - coff;
      }
    }
  }
  __syncthreads();
  const int d = threadIdx.x * 2;
  float a0 = 0.f, a1 = 0.f;
  const float* Vs[3] = {V0, V1, V2};
  const int smax[3] = {16383, 8191, 4095};
#pragma unroll
  for (int lev = 0; lev < 3; ++lev) {
    float t0 = tvS[lev][0], t1 = tvS[lev][1], t2 = tvS[lev][2], t3 = tvS[lev][3];
    float m = fmaxf(fmaxf(t0, t1), fmaxf(t2, t3));
    float e0 = __expf(t0 - m), e1 = __expf(t1 - m), e2 = __expf(t2 - m), e3 = __expf(t3 - m);
    float inv = 1.0f / (e0 + e1 + e2 + e3);
    float w4[4] = {e0 * inv, e1 * inv, e2 * inv, e3 * inv};
#pragma unroll
    for (int k = 0; k < 4; ++k) {
      int idx = tiS[lev][k];
      idx = idx < 0 ? 0 : (idx > smax[lev] ? smax[lev] : idx);  // safety clamp
      const float* vr = Vs[lev] + (long)idx * 512;
      a0 += w4[k] * vr[d];
      a1 += w4[k] * vr[d + 1];
    }
  }
  bf16x2 o = {(bf16_t)(a0 * (1.0f / 3.0f)), (bf16_t)(a1 * (1.0f / 3.0f))};
  *(bf16x2*)(readb + (long)r * 512 + d) = o;
}

// ---------------- host ----------------
extern "C" void kernel_launch(void* const* d_in, const int* in_sizes, int n_in,
                              void* d_out, int out_size, void* d_ws, size_t ws_size,
                              hipStream_t stream) {
  (void)in_sizes; (void)n_in; (void)out_size; (void)ws_size;
  const int* ids = (const int*)d_in[0];
  const float* tok = (const float*)d_in[1];
  const float* pos = (const float*)d_in[2];
  const float* Wqkv = (const float*)d_in[3];
  const float* bqkv = (const float*)d_in[4];
  const float* Wo = (const float*)d_in[5];
  const float* bo = (const float*)d_in[6];
  const float* ln1s = (const float*)d_in[7];
  const float* ln1b = (const float*)d_in[8];
  const float* W1 = (const float*)d_in[9];
  const float* b1 = (const float*)d_in[10];
  const float* W2 = (const float*)d_in[11];
  const float* b2 = (const float*)d_in[12];
  const float* ln2s = (const float*)d_in[13];
  const float* ln2b = (const float*)d_in[14];
  const float* Wq = (const float*)d_in[15];
  const float* bq = (const float*)d_in[16];
  const float* Wrp = (const float*)d_in[17];
  const float* brp = (const float*)d_in[18];
  const float* lnos = (const float*)d_in[19];
  const float* lnob = (const float*)d_in[20];
  const float* K0 = (const float*)d_in[21];
  const float* V0 = (const float*)d_in[22];
  const float* s0 = (const float*)d_in[23];
  const float* K1 = (const float*)d_in[24];
  const float* V1 = (const float*)d_in[25];
  const float* s1 = (const float*)d_in[26];
  const float* K2 = (const float*)d_in[27];
  const float* V2 = (const float*)d_in[28];
  const float* s2 = (const float*)d_in[29];

  char* wp = (char*)d_ws;
  auto walloc = [&](size_t bytes) -> char* {
    char* p = wp; wp += (bytes + 255) & ~(size_t)255; return p;
  };
  char* op = (char*)d_out;
  auto oalloc = [&](size_t bytes) -> char* {
    char* p = op; op += (bytes + 255) & ~(size_t)255; return p;
  };

  // transients in d_out (all reads complete before lm_head overwrites d_out)
  bf16_t* Wqkvb = (bf16_t*)oalloc(3145728ULL * 2);
  bf16_t* Wob   = (bf16_t*)oalloc(1048576ULL * 2);
  bf16_t* W1b   = (bf16_t*)oalloc(4194304ULL * 2);
  bf16_t* W2b   = (bf16_t*)oalloc(4194304ULL * 2);
  bf16_t* Wqb   = (bf16_t*)oalloc(262144ULL * 2);
  bf16_t* Wrpb  = (bf16_t*)oalloc(262144ULL * 2);
  bf16_t* Kb    = (bf16_t*)oalloc(28672ULL * 512 * 2);
  bf16_t* hb    = (bf16_t*)oalloc(4096ULL * 2048 * 2);
  u32*    cand  = (u32*)oalloc(4096ULL * 224 * 4 * 4);
  bf16_t* delta = (bf16_t*)oalloc(2ULL * 4096 * 512 * 2);  // 2 bf16 K-split partials

  // survivors in d_ws
  bf16_t* tokb = (bf16_t*)walloc(16384000ULL * 2);
  float*  x    = (float*)walloc(4096ULL * 512 * 4);
  bf16_t* xb   = (bf16_t*)walloc(4096ULL * 512 * 2);
  bf16_t* qh   = (bf16_t*)walloc(2097152ULL * 2);
  bf16_t* kh   = (bf16_t*)walloc(2097152ULL * 2);
  bf16_t* vt   = (bf16_t*)walloc(2097152ULL * 2);
  bf16_t* attob = (bf16_t*)walloc(4096ULL * 512 * 2);
  bf16_t* qmb  = (bf16_t*)walloc(4096ULL * 512 * 2);
  bf16_t* readb = (bf16_t*)walloc(4096ULL * 512 * 2);
  bf16_t* xfb  = (bf16_t*)walloc(4096ULL * 512 * 2);

  // all f32->bf16 conversions + embedding in one launch
  F2BArgs fa;
  fa.s[0] = tok;  fa.d[0] = tokb;  fa.n4[0] = 4096000;
  fa.s[1] = Wqkv; fa.d[1] = Wqkvb; fa.n4[1] = 786432;
  fa.s[2] = Wo;   fa.d[2] = Wob;   fa.n4[2] = 262144;
  fa.s[3] = W1;   fa.d[3] = W1b;   fa.n4[3] = 1048576;
  fa.s[4] = W2;   fa.d[4] = W2b;   fa.n4[4] = 1048576;
  fa.s[5] = Wq;   fa.d[5] = Wqb;   fa.n4[5] = 65536;
  fa.s[6] = Wrp;  fa.d[6] = Wrpb;  fa.n4[6] = 65536;
  fa.s[7] = K0;   fa.d[7] = Kb;                fa.n4[7] = 2097152;
  fa.s[8] = K1;   fa.d[8] = Kb + 8388608L;     fa.n4[8] = 1048576;
  fa.s[9] = K2;   fa.d[9] = Kb + 12582912L;    fa.n4[9] = 524288;
  fa.ids = ids; fa.pos = pos; fa.x = x; fa.xb = xb;
  k_f2b_all<<<dim3(128, 11), 256, 0, stream>>>(fa);

  const long long sCz = 4096LL * 512;
  for (int i = 0; i < 4; ++i) {
    // QKV GEMM (64-row tiles, 768 blocks = 3/CU) with fused split epilogue
    k_gemm64<bf16_t, true, 1><<<dim3(12, 64, 1), 256, 0, stream>>>(
        xb, 512, Wqkvb + (long long)i * 786432, 512, (bf16_t*)nullptr, 0, 0LL,
        bqkv + i * 1536, 512, 1.0f, qh, kh, vt);
    k_flash<<<dim3(32, 16), 256, 0, stream>>>(qh, kh, vt, attob);
    // Wo GEMM K-split (2 x K=256) -> bf16 delta partials
    k_gemm64<bf16_t, true><<<dim3(4, 64, 2), 256, 0, stream>>>(
        attob, 512, Wob + (long long)i * 262144, 512, delta, 512, sCz,
        bo + i * 512, 256, 1.0f, nullptr, nullptr, nullptr);
    k_ln2<<<4096, 256, 0, stream>>>(x, delta, delta + sCz,
                                    ln1s + i * 512, ln1b + i * 512, x, xb);
    // W1 GEMM + gelu (64-row tiles, 1024 blocks = 4/CU)
    k_gemm64<bf16_t, true, 2><<<dim3(16, 64, 1), 256, 0, stream>>>(
        xb, 512, W1b + (long long)i * 1048576, 512, hb, 2048, 0LL,
        b1 + i * 2048, 512, 1.0f, nullptr, nullptr, nullptr);
    // W2 GEMM K-split (2 x K=1024) -> bf16 delta partials
    k_gemm64<bf16_t, true><<<dim3(4, 64, 2), 256, 0, stream>>>(
        hb, 2048, W2b + (long long)i * 1048576, 2048, delta, 512, sCz,
        b2 + i * 512, 1024, 1.0f, nullptr, nullptr, nullptr);
    k_ln2<<<4096, 256, 0, stream>>>(x, delta, delta + sCz,
                                    ln2s + i * 512, ln2b + i * 512, x, xb);
  }

  // memory path: qm = (x@Wq^T + bq)/sqrt(512) in bf16
  k_gemm64<bf16_t, true><<<dim3(4, 64, 1), 256, 0, stream>>>(
      xb, 512, Wqb, 512, qmb, 512, 0LL, bq, 512, 0.044194173824159216f,
      nullptr, nullptr, nullptr);
  // score GEMM over concatenated banks, fused salience + per-block top-4 -> cand
  k_gemm_bt<bf16_t, false, 3><<<dim3(224, 32), 256, 0, stream>>>(
      qmb, 512, Kb, 512, (bf16_t*)nullptr, 0, nullptr, 512, 1.0f, s0, s1, s2, cand);
  // merge candidates + gather V in one launch
  k_topkread<<<4096, 256, 0, stream>>>(cand, V0, V1, V2, readb);
  // Wrp GEMM K-split + final LN
  k_gemm64<bf16_t, true><<<dim3(4, 64, 2), 256, 0, stream>>>(
      readb, 512, Wrpb, 512, delta, 512, sCz, brp, 256, 1.0f,
      nullptr, nullptr, nullptr);
  k_ln2<<<4096, 256, 0, stream>>>(x, delta, delta + sCz, lnos, lnob, nullptr, xfb);
  // logits = x @ tok_embed^T  (f32, overwrites all d_out scratch)
  k_gemm_bt<float, false, 0><<<dim3(250, 32), 256, 0, stream>>>(
      xfb, 512, tokb, 512, (float*)d_out, 32000, nullptr, 512, 1.0f,
      nullptr, nullptr, nullptr, nullptr);
}

// Round 18
// 1107.063 us; speedup vs baseline: 1.0623x; 1.0623x over previous
//
#include <hip/hip_runtime.h>
#include <cstdint>

typedef __bf16 bf16_t;
typedef __bf16 bf16x2 __attribute__((ext_vector_type(2)));
typedef __bf16 bf16x4 __attribute__((ext_vector_type(4)));
typedef __bf16 bf16x8 __attribute__((ext_vector_type(8)));
typedef float f32x4 __attribute__((ext_vector_type(4)));
typedef unsigned short u16;
typedef unsigned int u32;
typedef unsigned short u16x8 __attribute__((ext_vector_type(8)));

#define DEVI static __device__ __forceinline__

// async global->LDS, 16B per lane; LDS dest = wave-uniform base + lane*16
DEVI void g2l16(const void* g, void* l) {
  __builtin_amdgcn_global_load_lds((__attribute__((address_space(1))) void*)g,
                                   (__attribute__((address_space(3))) void*)l,
                                   16, 0, 0);
}

// sorted-desc top-4 insert of packed u32 keys
DEVI void tki4(u32* k, u32 nk) {
  if (nk <= k[3]) return;
  k[3] = nk;
  if (k[3] > k[2]) { u32 t = k[2]; k[2] = k[3]; k[3] = t; }
  if (k[2] > k[1]) { u32 t = k[1]; k[1] = k[2]; k[2] = t; }
  if (k[1] > k[0]) { u32 t = k[0]; k[0] = k[1]; k[1] = t; }
}

// ---------------- fused f32->bf16 convert + embedding (one launch) ----------------
struct F2BArgs {
  const float* s[10];
  bf16_t* d[10];
  int n4[10];
  const int* ids;
  const float* pos;
  float* x;
  bf16_t* xb;
};
__global__ void k_f2b_all(F2BArgs a) {
  const int seg = blockIdx.y;
  if (seg == 10) {
    const int d = threadIdx.x * 2;
    for (int r = blockIdx.x; r < 4096; r += gridDim.x) {
      const int t = r & 2047;
      const long id = a.ids[r];
      float2 av = *(const float2*)(a.s[0] + id * 512 + d);
      float2 p = *(const float2*)(a.pos + (long)t * 512 + d);
      float o0 = av.x + p.x, o1 = av.y + p.y;
      *(float2*)(a.x + (long)r * 512 + d) = make_float2(o0, o1);
      bf16x2 ob = {(bf16_t)o0, (bf16_t)o1};
      *(bf16x2*)(a.xb + (long)r * 512 + d) = ob;
    }
    return;
  }
  const float* __restrict__ in = a.s[seg];
  bf16_t* __restrict__ out = a.d[seg];
  const long n4 = a.n4[seg];
  const long stride = (long)gridDim.x * blockDim.x;
  for (long i = (long)blockIdx.x * blockDim.x + threadIdx.x; i < n4; i += stride) {
    float4 v = ((const float4*)in)[i];
    bf16x4 o = {(bf16_t)v.x, (bf16_t)v.y, (bf16_t)v.z, (bf16_t)v.w};
    ((bf16x4*)out)[i] = o;
  }
}

DEVI float gelu_f(float f) {
  return 0.5f * f * (1.0f + erff(f * 0.70710678118654752f));
}

// ---------------- 128x128 GEMM, 4-slot counted-vmcnt pipeline ----------------
// EPI: 0 plain store; 2 gelu->bf16; 3 score top-4 -> cand[M][224][4].
template <typename CT, bool BIAS, int EPI>
__global__ __launch_bounds__(256, 2) void k_gemm_bt(
    const bf16_t* __restrict__ A, int lda, const bf16_t* __restrict__ B, int ldb,
    CT* __restrict__ C, int ldc, const float* __restrict__ bias, int K, float alpha,
    const float* __restrict__ s0, const float* __restrict__ s1,
    const float* __restrict__ s2, u32* __restrict__ cand) {
  __shared__ bf16_t As[4][4096];  // slot x [128][32]
  __shared__ bf16_t Bs[4][4096];
  const int tid = threadIdx.x;
  const int lane = tid & 63;
  const int w = tid >> 6;
  const int wm = w >> 1, wn = w & 1;
  const int m0 = blockIdx.y * 128;
  const int n0 = blockIdx.x * 128;

  f32x4 acc[4][4];
#pragma unroll
  for (int m = 0; m < 4; ++m)
#pragma unroll
    for (int n = 0; n < 4; ++n) acc[m][n] = (f32x4){0.f, 0.f, 0.f, 0.f};

  const int srow = tid >> 2;
  const int scol = ((tid & 3) ^ ((srow >> 1) & 3)) * 8;  // pre-swizzled source granule
  const int fr = lane & 15;
  const int g4 = lane >> 4;
  const int kg = g4 * 8;
  const int NT = K >> 5;

  auto stage = [&](int kp) {
    const int slot = kp & 3;
    bf16_t* as = As[slot];
    bf16_t* bs = Bs[slot];
    const int k0 = kp * 32;
    g2l16(A + (long long)(m0 + srow) * lda + (k0 + scol), as + tid * 8);
    g2l16(A + (long long)(m0 + 64 + srow) * lda + (k0 + scol), as + 2048 + tid * 8);
    g2l16(B + (long long)(n0 + srow) * ldb + (k0 + scol), bs + tid * 8);
    g2l16(B + (long long)(n0 + 64 + srow) * ldb + (k0 + scol), bs + 2048 + tid * 8);
  };

  stage(0);
  stage(1);
  asm volatile("s_waitcnt vmcnt(4)" ::: "memory");
  __builtin_amdgcn_s_barrier();
  __builtin_amdgcn_sched_barrier(0);

  for (int k = 0; k < NT; ++k) {
    const int slot = k & 3;
    const bf16_t* as = As[slot];
    const bf16_t* bs = Bs[slot];
    bf16x8 fa[4], fb[4];
#pragma unroll
    for (int m = 0; m < 4; ++m) {
      const int row = wm * 64 + m * 16 + fr;
      fa[m] = *(const bf16x8*)(as + row * 32 + (kg ^ (((row >> 1) & 3) << 3)));
    }
#pragma unroll
    for (int n = 0; n < 4; ++n) {
      const int row = wn * 64 + n * 16 + fr;
      fb[n] = *(const bf16x8*)(bs + row * 32 + (kg ^ (((row >> 1) & 3) << 3)));
    }
    if (k + 2 < NT) stage(k + 2);
    if (k < NT - 2) {
      asm volatile("s_waitcnt vmcnt(4)" ::: "memory");
    } else {
      asm volatile("s_waitcnt vmcnt(0)" ::: "memory");
    }
    __builtin_amdgcn_s_barrier();
    __builtin_amdgcn_sched_barrier(0);
    __builtin_amdgcn_s_setprio(1);
#pragma unroll
    for (int m = 0; m < 4; ++m)
#pragma unroll
      for (int n = 0; n < 4; ++n)
        acc[m][n] = __builtin_amdgcn_mfma_f32_16x16x32_bf16(fa[m], fb[n], acc[m][n], 0, 0, 0);
    __builtin_amdgcn_s_setprio(0);
  }

  if (EPI == 3) {
    // ---- score epilogue: add salience, block-local per-row top-4 -> cand ----
    const float* salp;
    if (n0 < 16384) salp = s0 + n0;
    else if (n0 < 24576) salp = s1 + (n0 - 16384);
    else salp = s2 + (n0 - 24576);
    float bv[4];
    int coll[4];
#pragma unroll
    for (int n = 0; n < 4; ++n) {
      coll[n] = wn * 64 + n * 16 + fr;
      bv[n] = salp[coll[n]];
    }
    __syncthreads();
    u16* slab = (u16*)&As[0][0];  // [128 rows][128 cols] bf16, col idx XOR (row&7)<<3
#pragma unroll
    for (int m = 0; m < 4; ++m) {
#pragma unroll
      for (int r = 0; r < 4; ++r) {
        const int rl = wm * 64 + m * 16 + g4 * 4 + r;
        const int sw = (rl & 7) << 3;
#pragma unroll
        for (int n = 0; n < 4; ++n) {
          bf16_t bvv = (bf16_t)(acc[m][n][r] + bv[n]);
          slab[rl * 128 + (coll[n] ^ sw)] = __builtin_bit_cast(u16, bvv);
        }
      }
    }
    __syncthreads();
    const int rr = tid & 127;
    const int hh = tid >> 7;
    const int sw = (rr & 7) << 3;
    u32 rk[4] = {0u, 0u, 0u, 0u};
    const u32 ibase = 0x7FFFu - (u32)n0;
    u32* res = (u32*)&Bs[0][0];
#pragma unroll
    for (int j = 0; j < 8; ++j) {
      const int c0 = hh * 64 + j * 8;
      u16x8 vv = *(const u16x8*)(slab + rr * 128 + (c0 ^ sw));
#pragma unroll
      for (int e = 0; e < 8; ++e) {
        u16 sb = vv[e];
        u32 k16 = (u32)sb ^ (0x8000u | (0x7FFFu * (u32)(sb >> 15)));
        tki4(rk, (k16 << 15) | (ibase - (u32)(c0 + e)));
      }
    }
#pragma unroll
    for (int j = 0; j < 4; ++j) res[(rr * 2 + hh) * 4 + j] = rk[j];
    __syncthreads();
    if (tid < 128) {
      const u32* rp = res + tid * 8;
      u32 fin[4] = {rp[0], rp[1], rp[2], rp[3]};
      tki4(fin, rp[4]); tki4(fin, rp[5]); tki4(fin, rp[6]); tki4(fin, rp[7]);
      u32* cp = cand + ((long long)(m0 + tid) * 224 + (n0 >> 7)) * 4;
#pragma unroll
      for (int j = 0; j < 4; ++j) cp[j] = fin[j];
    }
    return;
  }

#pragma unroll
  for (int n = 0; n < 4; ++n) {
    const int col = n0 + wn * 64 + n * 16 + fr;
    const float bv = BIAS ? bias[col] : 0.0f;
#pragma unroll
    for (int m = 0; m < 4; ++m) {
      const long long rb = m0 + wm * 64 + m * 16 + g4 * 4;
#pragma unroll
      for (int r = 0; r < 4; ++r) {
        float v = (acc[m][n][r] + bv) * alpha;
        if (EPI == 2) v = gelu_f(v);
        C[(rb + r) * (long long)ldc + col] = (CT)v;
      }
    }
  }
}

// ---------------- 64x128 GEMM, K-split over z, 3-slot counted-vmcnt pipeline ----------------
// EPI: 0 plain store; 1 qkv split (q*0.125->qh, k->kh, v->vt); 2 gelu->bf16.
template <typename CT, bool BIAS, int EPI = 0>
__global__ __launch_bounds__(256, 4) void k_gemm64(
    const bf16_t* __restrict__ A, int lda, const bf16_t* __restrict__ B, int ldb,
    CT* __restrict__ C, int ldc, long long sCz, const float* __restrict__ bias,
    int K, float alpha, bf16_t* __restrict__ qh, bf16_t* __restrict__ kh,
    bf16_t* __restrict__ vt) {
  __shared__ bf16_t As[3][2048];  // slot x [64][32]
  __shared__ bf16_t Bs[3][4096];  // slot x [128][32]
  const int tid = threadIdx.x;
  const int lane = tid & 63;
  const int w = tid >> 6;
  const int wm = w >> 1, wn = w & 1;
  const int m0 = blockIdx.y * 64;
  const int n0 = blockIdx.x * 128;
  const int kz = blockIdx.z;
  A += (long long)kz * K;
  B += (long long)kz * K;
  C += (long long)kz * sCz;

  f32x4 acc[2][4];
#pragma unroll
  for (int m = 0; m < 2; ++m)
#pragma unroll
    for (int n = 0; n < 4; ++n) acc[m][n] = (f32x4){0.f, 0.f, 0.f, 0.f};

  const int srow = tid >> 2;
  const int scol = ((tid & 3) ^ ((srow >> 1) & 3)) * 8;  // pre-swizzled source granule
  const int fr = lane & 15;
  const int g4 = lane >> 4;
  const int kg = g4 * 8;
  const int NT = K >> 5;

  auto stage = [&](int kp) {
    const int slot = kp % 3;
    bf16_t* as = As[slot];
    bf16_t* bs = Bs[slot];
    const int k0 = kp * 32;
    g2l16(A + (long long)(m0 + srow) * lda + (k0 + scol), as + tid * 8);
    g2l16(B + (long long)(n0 + srow) * ldb + (k0 + scol), bs + tid * 8);
    g2l16(B + (long long)(n0 + 64 + srow) * ldb + (k0 + scol), bs + 2048 + tid * 8);
  };

  stage(0);
  stage(1);
  asm volatile("s_waitcnt vmcnt(3)" ::: "memory");
  __builtin_amdgcn_s_barrier();
  __builtin_amdgcn_sched_barrier(0);

  for (int k = 0; k < NT; ++k) {
    const int slot = k % 3;
    const bf16_t* as = As[slot];
    const bf16_t* bs = Bs[slot];
    bf16x8 fa[2], fb[4];
#pragma unroll
    for (int m = 0; m < 2; ++m) {
      const int row = wm * 32 + m * 16 + fr;
      fa[m] = *(const bf16x8*)(as + row * 32 + (kg ^ (((row >> 1) & 3) << 3)));
    }
#pragma unroll
    for (int n = 0; n < 4; ++n) {
      const int row = wn * 64 + n * 16 + fr;
      fb[n] = *(const bf16x8*)(bs + row * 32 + (kg ^ (((row >> 1) & 3) << 3)));
    }
    if (k + 2 < NT) stage(k + 2);
    if (k < NT - 2) {
      asm volatile("s_waitcnt vmcnt(3)" ::: "memory");
    } else {
      asm volatile("s_waitcnt vmcnt(0)" ::: "memory");
    }
    __builtin_amdgcn_s_barrier();
    __builtin_amdgcn_sched_barrier(0);
    __builtin_amdgcn_s_setprio(1);
#pragma unroll
    for (int m = 0; m < 2; ++m)
#pragma unroll
      for (int n = 0; n < 4; ++n)
        acc[m][n] = __builtin_amdgcn_mfma_f32_16x16x32_bf16(fa[m], fb[n], acc[m][n], 0, 0, 0);
    __builtin_amdgcn_s_setprio(0);
  }

#pragma unroll
  for (int n = 0; n < 4; ++n) {
    const int col = n0 + wn * 64 + n * 16 + fr;
    const float bv = (BIAS && kz == 0) ? bias[col] : 0.0f;
    if (EPI == 1) {
      const int reg = col >> 9;
      const int h = (col >> 6) & 7;
      const int hd = col & 63;
#pragma unroll
      for (int m = 0; m < 2; ++m) {
        const int rb = m0 + wm * 32 + m * 16 + g4 * 4;
#pragma unroll
        for (int r = 0; r < 4; ++r) {
          const int row = rb + r;
          const int b = row >> 11, t = row & 2047;
          const long long bh = (long long)b * 8 + h;
          float v = acc[m][n][r] + bv;
          if (reg == 0) qh[(bh * 2048 + t) * 64 + hd] = (bf16_t)(v * 0.125f);
          else if (reg == 1) kh[(bh * 2048 + t) * 64 + hd] = (bf16_t)v;
          else vt[(bh * 64 + hd) * 2048 + t] = (bf16_t)v;
        }
      }
    } else {
#pragma unroll
      for (int m = 0; m < 2; ++m) {
        const long long rb = m0 + wm * 32 + m * 16 + g4 * 4;
#pragma unroll
        for (int r = 0; r < 4; ++r) {
          float v = (acc[m][n][r] + bv) * alpha;
          if (EPI == 2) v = gelu_f(v);
          C[(rb + r) * (long long)ldc + col] = (CT)v;
        }
      }
    }
  }
}

// ---------------- fused flash attention (QBLK=64, KVBLK=128, 512 blocks = 2/CU) ----------------
__global__ __launch_bounds__(256, 2) void k_flash(
    const bf16_t* __restrict__ qh, const bf16_t* __restrict__ kh,
    const bf16_t* __restrict__ vt, bf16_t* __restrict__ out) {
  __shared__ bf16_t Ks[2][128 * 64];
  __shared__ bf16_t Vs[2][64 * 128];
  __shared__ bf16_t Ps[4 * 16 * 128];
  const int tid = threadIdx.x;
  const int lane = tid & 63;
  const int w = tid >> 6;
  const int bh = blockIdx.y;
  const int q0 = blockIdx.x * 64;
  const int fr = lane & 15;
  const int g4 = lane >> 4;
  const int kg = g4 * 8;

  bf16x8 qf[2];
  {
    const bf16_t* qb = qh + ((long long)bh * 2048 + q0 + w * 16) * 64;
#pragma unroll
    for (int ks = 0; ks < 2; ++ks)
      qf[ks] = *(const bf16x8*)(qb + fr * 64 + ks * 32 + kg);
  }

  f32x4 oacc[4];
#pragma unroll
  for (int n = 0; n < 4; ++n) oacc[n] = (f32x4){0.f, 0.f, 0.f, 0.f};
  float li[4] = {0.f, 0.f, 0.f, 0.f};

  char* PsW = (char*)(Ps + w * 16 * 128);
  const bf16_t* kbase = kh + (long long)bh * 2048 * 64;
  const bf16_t* vbase = vt + (long long)bh * 64 * 2048;

  auto stage = [&](int kt, int buf) {
#pragma unroll
    for (int i = 0; i < 4; ++i) {
      int row = (w * 4 + i) * 8 + (lane >> 3);
      int c = lane & 7;
      g2l16(kbase + ((long long)(kt * 128 + row)) * 64 + (c ^ (row & 7)) * 8,
            Ks[buf] + (w * 4 + i) * 512);
      int d = w * 16 + i * 4 + (lane >> 4);
      int c2 = lane & 15;
      g2l16(vbase + (long long)d * 2048 + kt * 128 + ((c2 ^ (d & 7)) * 8),
            Vs[buf] + (w * 16 + i * 4) * 128);
    }
  };

  stage(0, 0);
  int buf = 0;
  for (int kt = 0; kt < 16; ++kt) {
    __syncthreads();
    if (kt + 1 < 16) stage(kt + 1, buf ^ 1);

    f32x4 s[8];
#pragma unroll
    for (int n = 0; n < 8; ++n) s[n] = (f32x4){0.f, 0.f, 0.f, 0.f};
#pragma unroll
    for (int ks = 0; ks < 2; ++ks) {
#pragma unroll
      for (int n = 0; n < 8; ++n) {
        int row = n * 16 + fr;
        bf16x8 kf = *(const bf16x8*)((const char*)Ks[buf] + row * 128 +
                                     ((ks * 64 + kg * 2) ^ ((row & 7) << 4)));
        s[n] = __builtin_amdgcn_mfma_f32_16x16x32_bf16(qf[ks], kf, s[n], 0, 0, 0);
      }
    }

#pragma unroll
    for (int r = 0; r < 4; ++r) {
      const int lr = g4 * 4 + r;
      const int sw = (lr & 7) << 4;
      float rs = 0.f;
#pragma unroll
      for (int n = 0; n < 8; ++n) {
        float p = __expf(s[n][r]);
        rs += p;
        *(bf16_t*)(PsW + lr * 256 + (((n * 16 + fr) * 2) ^ sw)) = (bf16_t)p;
      }
      li[r] += rs;
    }

#pragma unroll
    for (int ks = 0; ks < 4; ++ks) {
      bf16x8 pa = *(const bf16x8*)(PsW + fr * 256 +
                                   ((ks * 64 + kg * 2) ^ ((fr & 7) << 4)));
#pragma unroll
      for (int n = 0; n < 4; ++n) {
        int d = n * 16 + fr;
        bf16x8 vf = *(const bf16x8*)((const char*)Vs[buf] + d * 256 +
                                     ((ks * 64 + kg * 2) ^ ((d & 7) << 4)));
        oacc[n] = __builtin_amdgcn_mfma_f32_16x16x32_bf16(pa, vf, oacc[n], 0, 0, 0);
      }
    }
    buf ^= 1;
  }

#pragma unroll
  for (int r = 0; r < 4; ++r) {
    li[r] += __shfl_xor(li[r], 1);
    li[r] += __shfl_xor(li[r], 2);
    li[r] += __shfl_xor(li[r], 4);
    li[r] += __shfl_xor(li[r], 8);
  }

  const int b = bh >> 3, h = bh & 7;
  bf16_t* ob = out + ((long long)b * 2048 + q0 + w * 16) * 512 + h * 64;
#pragma unroll
  for (int r = 0; r < 4; ++r) {
    float inv = 1.0f / li[r];
#pragma unroll
    for (int n = 0; n < 4; ++n)
      ob[(g4 * 4 + r) * 512 + n * 16 + fr] = (bf16_t)(oacc[n][r] * inv);
  }
}

// ---------------- LN(xin + d1 + d2) * s + b -> xout (f32) + xbf (bf16), D=512 ----------------
// d1/d2 are bf16 K-split partials.
__global__ void k_ln2(const float* __restrict__ xin, const bf16_t* __restrict__ d1,
                      const bf16_t* __restrict__ d2, const float* __restrict__ s,
                      const float* __restrict__ b, float* __restrict__ xout,
                      bf16_t* __restrict__ xbf) {
  __shared__ float red[8];
  const int r = blockIdx.x;
  const int tid = threadIdx.x;
  const int d = tid * 2;
  const int lane = tid & 63, w = tid >> 6;
  float2 xi = *(const float2*)(xin + (long)r * 512 + d);
  bf16x2 e1 = *(const bf16x2*)(d1 + (long)r * 512 + d);
  bf16x2 e2 = *(const bf16x2*)(d2 + (long)r * 512 + d);
  float y0 = xi.x + (float)e1[0] + (float)e2[0];
  float y1 = xi.y + (float)e1[1] + (float)e2[1];
  float sum = y0 + y1, ss = y0 * y0 + y1 * y1;
#pragma unroll
  for (int o = 32; o > 0; o >>= 1) { sum += __shfl_xor(sum, o); ss += __shfl_xor(ss, o); }
  if (lane == 0) { red[w] = sum; red[4 + w] = ss; }
  __syncthreads();
  sum = red[0] + red[1] + red[2] + red[3];
  ss = red[4] + red[5] + red[6] + red[7];
  const float mean = sum * (1.0f / 512.0f);
  const float var = ss * (1.0f / 512.0f) - mean * mean;
  const float rstd = rsqrtf(var + 1e-5f);
  float o0 = (y0 - mean) * rstd * s[d] + b[d];
  float o1 = (y1 - mean) * rstd * s[d + 1] + b[d + 1];
  if (xout) *(float2*)(xout + (long)r * 512 + d) = make_float2(o0, o1);
  bf16x2 ob = {(bf16_t)o0, (bf16_t)o1};
  *(bf16x2*)(xbf + (long)r * 512 + d) = ob;
}

// ---------------- fused: merge candidates (waves 0-2, one level each) + gather V ----------------
__global__ void k_topkread(const u32* __restrict__ cand, const float* __restrict__ V0,
                           const float* __restrict__ V1, const float* __restrict__ V2,
                           bf16_t* __restrict__ readb) {
  __shared__ float tvS[3][4];
  __shared__ int tiS[3][4];
  const int r = blockIdx.x;
  const int lane = threadIdx.x & 63;
  const int w = threadIdx.x >> 6;
  if (w < 3) {
    const int cnt = w == 0 ? 128 : (w == 1 ? 64 : 32);
    const int base = w == 0 ? 0 : (w == 1 ? 128 : 192);
    const int coff = w == 0 ? 0 : (w == 1 ? 16384 : 24576);
    const u32* cr = cand + (long long)r * 224 + base;
    u32 rk[4] = {0u, 0u, 0u, 0u};
    for (int j = lane; j < cnt; j += 64) tki4(rk, cr[j]);
#pragma unroll
    for (int dd = 1; dd < 64; dd <<= 1) {
      u32 o[4];
#pragma unroll
      for (int j = 0; j < 4; ++j) o[j] = (u32)__shfl_xor((int)rk[j], dd);
#pragma unroll
      for (int j = 0; j < 4; ++j) tki4(rk, o[j]);
    }
    if (lane == 0) {
#pragma unroll
      for (int j = 0; j < 4; ++j) {
        u32 k16 = rk[j] >> 15;
        u16 b = (k16 & 0x8000u) ? (u16)(k16 ^ 0x8000u) : (u16)(~k16);
        u32 fb = ((u32)b) << 16;
        tvS[w][j] = __uint_as_float(fb);
        tiS[w][j] = (0x7FFF - (int)(rk[j] & 0x7FFF)) - coff;
      }
    }
  }
  __syncthreads();
  const int d = threadIdx.x * 2;
  float a0 = 0.f, a1 = 0.f;
  const float* Vs[3] = {V0, V1, V2};
  const int smax[3] = {16383, 8191, 4095};
#pragma unroll
  for (int lev = 0; lev < 3; ++lev) {
    float t0 = tvS[lev][0], t1 = tvS[lev][1], t2 = tvS[lev][2], t3 = tvS[lev][3];
    float m = fmaxf(fmaxf(t0, t1), fmaxf(t2, t3));
    float e0 = __expf(t0 - m), e1 = __expf(t1 - m), e2 = __expf(t2 - m), e3 = __expf(t3 - m);
    float inv = 1.0f / (e0 + e1 + e2 + e3);
    float w4[4] = {e0 * inv, e1 * inv, e2 * inv, e3 * inv};
#pragma unroll
    for (int k = 0; k < 4; ++k) {
      int idx = tiS[lev][k];
      idx = idx < 0 ? 0 : (idx > smax[lev] ? smax[lev] : idx);  // safety clamp
      const float* vr = Vs[lev] + (long)idx * 512;
      a0 += w4[k] * vr[d];
      a1 += w4[k] * vr[d + 1];
    }
  }
  bf16x2 o = {(bf16_t)(a0 * (1.0f / 3.0f)), (bf16_t)(a1 * (1.0f / 3.0f))};
  *(bf16x2*)(readb + (long)r * 512 + d) = o;
}

// ---------------- host ----------------
extern "C" void kernel_launch(void* const* d_in, const int* in_sizes, int n_in,
                              void* d_out, int out_size, void* d_ws, size_t ws_size,
                              hipStream_t stream) {
  (void)in_sizes; (void)n_in; (void)out_size; (void)ws_size;
  const int* ids = (const int*)d_in[0];
  const float* tok = (const float*)d_in[1];
  const float* pos = (const float*)d_in[2];
  const float* Wqkv = (const float*)d_in[3];
  const float* bqkv = (const float*)d_in[4];
  const float* Wo = (const float*)d_in[5];
  const float* bo = (const float*)d_in[6];
  const float* ln1s = (const float*)d_in[7];
  const float* ln1b = (const float*)d_in[8];
  const float* W1 = (const float*)d_in[9];
  const float* b1 = (const float*)d_in[10];
  const float* W2 = (const float*)d_in[11];
  const float* b2 = (const float*)d_in[12];
  const float* ln2s = (const float*)d_in[13];
  const float* ln2b = (const float*)d_in[14];
  const float* Wq = (const float*)d_in[15];
  const float* bq = (const float*)d_in[16];
  const float* Wrp = (const float*)d_in[17];
  const float* brp = (const float*)d_in[18];
  const float* lnos = (const float*)d_in[19];
  const float* lnob = (const float*)d_in[20];
  const float* K0 = (const float*)d_in[21];
  const float* V0 = (const float*)d_in[22];
  const float* s0 = (const float*)d_in[23];
  const float* K1 = (const float*)d_in[24];
  const float* V1 = (const float*)d_in[25];
  const float* s1 = (const float*)d_in[26];
  const float* K2 = (const float*)d_in[27];
  const float* V2 = (const float*)d_in[28];
  const float* s2 = (const float*)d_in[29];

  char* wp = (char*)d_ws;
  auto walloc = [&](size_t bytes) -> char* {
    char* p = wp; wp += (bytes + 255) & ~(size_t)255; return p;
  };
  char* op = (char*)d_out;
  auto oalloc = [&](size_t bytes) -> char* {
    char* p = op; op += (bytes + 255) & ~(size_t)255; return p;
  };

  // transients in d_out (all reads complete before lm_head overwrites d_out)
  bf16_t* Wqkvb = (bf16_t*)oalloc(3145728ULL * 2);
  bf16_t* Wob   = (bf16_t*)oalloc(1048576ULL * 2);
  bf16_t* W1b   = (bf16_t*)oalloc(4194304ULL * 2);
  bf16_t* W2b   = (bf16_t*)oalloc(4194304ULL * 2);
  bf16_t* Wqb   = (bf16_t*)oalloc(262144ULL * 2);
  bf16_t* Wrpb  = (bf16_t*)oalloc(262144ULL * 2);
  bf16_t* Kb    = (bf16_t*)oalloc(28672ULL * 512 * 2);
  bf16_t* hb    = (bf16_t*)oalloc(4096ULL * 2048 * 2);
  u32*    cand  = (u32*)oalloc(4096ULL * 224 * 4 * 4);
  bf16_t* delta = (bf16_t*)oalloc(2ULL * 4096 * 512 * 2);  // 2 bf16 K-split partials

  // survivors in d_ws
  bf16_t* tokb = (bf16_t*)walloc(16384000ULL * 2);
  float*  x    = (float*)walloc(4096ULL * 512 * 4);
  bf16_t* xb   = (bf16_t*)walloc(4096ULL * 512 * 2);
  bf16_t* qh   = (bf16_t*)walloc(2097152ULL * 2);
  bf16_t* kh   = (bf16_t*)walloc(2097152ULL * 2);
  bf16_t* vt   = (bf16_t*)walloc(2097152ULL * 2);
  bf16_t* attob = (bf16_t*)walloc(4096ULL * 512 * 2);
  bf16_t* qmb  = (bf16_t*)walloc(4096ULL * 512 * 2);
  bf16_t* readb = (bf16_t*)walloc(4096ULL * 512 * 2);
  bf16_t* xfb  = (bf16_t*)walloc(4096ULL * 512 * 2);

  // all f32->bf16 conversions + embedding in one launch
  F2BArgs fa;
  fa.s[0] = tok;  fa.d[0] = tokb;  fa.n4[0] = 4096000;
  fa.s[1] = Wqkv; fa.d[1] = Wqkvb; fa.n4[1] = 786432;
  fa.s[2] = Wo;   fa.d[2] = Wob;   fa.n4[2] = 262144;
  fa.s[3] = W1;   fa.d[3] = W1b;   fa.n4[3] = 1048576;
  fa.s[4] = W2;   fa.d[4] = W2b;   fa.n4[4] = 1048576;
  fa.s[5] = Wq;   fa.d[5] = Wqb;   fa.n4[5] = 65536;
  fa.s[6] = Wrp;  fa.d[6] = Wrpb;  fa.n4[6] = 65536;
  fa.s[7] = K0;   fa.d[7] = Kb;                fa.n4[7] = 2097152;
  fa.s[8] = K1;   fa.d[8] = Kb + 8388608L;     fa.n4[8] = 1048576;
  fa.s[9] = K2;   fa.d[9] = Kb + 12582912L;    fa.n4[9] = 524288;
  fa.ids = ids; fa.pos = pos; fa.x = x; fa.xb = xb;
  k_f2b_all<<<dim3(128, 11), 256, 0, stream>>>(fa);

  const long long sCz = 4096LL * 512;
  for (int i = 0; i < 4; ++i) {
    // QKV GEMM (64-row tiles, 768 blocks = 3/CU) with fused split epilogue
    k_gemm64<bf16_t, true, 1><<<dim3(12, 64, 1), 256, 0, stream>>>(
        xb, 512, Wqkvb + (long long)i * 786432, 512, (bf16_t*)nullptr, 0, 0LL,
        bqkv + i * 1536, 512, 1.0f, qh, kh, vt);
    k_flash<<<dim3(32, 16), 256, 0, stream>>>(qh, kh, vt, attob);
    // Wo GEMM K-split (2 x K=256) -> bf16 delta partials
    k_gemm64<bf16_t, true><<<dim3(4, 64, 2), 256, 0, stream>>>(
        attob, 512, Wob + (long long)i * 262144, 512, delta, 512, sCz,
        bo + i * 512, 256, 1.0f, nullptr, nullptr, nullptr);
    k_ln2<<<4096, 256, 0, stream>>>(x, delta, delta + sCz,
                                    ln1s + i * 512, ln1b + i * 512, x, xb);
    // W1 GEMM + gelu (64-row tiles, 1024 blocks = 4/CU)
    k_gemm64<bf16_t, true, 2><<<dim3(16, 64, 1), 256, 0, stream>>>(
        xb, 512, W1b + (long long)i * 1048576, 512, hb, 2048, 0LL,
        b1 + i * 2048, 512, 1.0f, nullptr, nullptr, nullptr);
    // W2 GEMM K-split (2 x K=1024) -> bf16 delta partials
    k_gemm64<bf16_t, true><<<dim3(4, 64, 2), 256, 0, stream>>>(
        hb, 2048, W2b + (long long)i * 1048576, 2048, delta, 512, sCz,
        b2 + i * 512, 1024, 1.0f, nullptr, nullptr, nullptr);
    k_ln2<<<4096, 256, 0, stream>>>(x, delta, delta + sCz,
                                    ln2s + i * 512, ln2b + i * 512, x, xb);
  }

  // memory path: qm = (x@Wq^T + bq)/sqrt(512) in bf16
  k_gemm64<bf16_t, true><<<dim3(4, 64, 1), 256, 0, stream>>>(
      xb, 512, Wqb, 512, qmb, 512, 0LL, bq, 512, 0.044194173824159216f,
      nullptr, nullptr, nullptr);
  // score GEMM over concatenated banks, fused salience + per-block top-4 -> cand
  k_gemm_bt<bf16_t, false, 3><<<dim3(224, 32), 256, 0, stream>>>(
      qmb, 512, Kb, 512, (bf16_t*)nullptr, 0, nullptr, 512, 1.0f, s0, s1, s2, cand);
  // merge candidates + gather V in one launch
  k_topkread<<<4096, 256, 0, stream>>>(cand, V0, V1, V2, readb);
  // Wrp GEMM K-split + final LN
  k_gemm64<bf16_t, true><<<dim3(4, 64, 2), 256, 0, stream>>>(
      readb, 512, Wrpb, 512, delta, 512, sCz, brp, 256, 1.0f,
      nullptr, nullptr, nullptr);
  k_ln2<<<4096, 256, 0, stream>>>(x, delta, delta + sCz, lnos, lnob, nullptr, xfb);
  // logits = x @ tok_embed^T  (f32, overwrites all d_out scratch)
  k_gemm_bt<float, false, 0><<<dim3(250, 32), 256, 0, stream>>>(
      xfb, 512, tokb, 512, (float*)d_out, 32000, nullptr, 512, 1.0f,
      nullptr, nullptr, nullptr, nullptr);
}

// Round 19
// 1058.253 us; speedup vs baseline: 1.1113x; 1.0461x over previous
//
#include <hip/hip_runtime.h>
#include <cstdint>

typedef __bf16 bf16_t;
typedef __bf16 bf16x2 __attribute__((ext_vector_type(2)));
typedef __bf16 bf16x4 __attribute__((ext_vector_type(4)));
typedef __bf16 bf16x8 __attribute__((ext_vector_type(8)));
typedef float f32x4 __attribute__((ext_vector_type(4)));
typedef unsigned short u16;
typedef unsigned int u32;
typedef unsigned short u16x8 __attribute__((ext_vector_type(8)));

#define DEVI static __device__ __forceinline__

// async global->LDS, 16B per lane; LDS dest = wave-uniform base + lane*16
DEVI void g2l16(const void* g, void* l) {
  __builtin_amdgcn_global_load_lds((__attribute__((address_space(1))) void*)g,
                                   (__attribute__((address_space(3))) void*)l,
                                   16, 0, 0);
}

// sorted-desc top-4 insert of packed u32 keys
DEVI void tki4(u32* k, u32 nk) {
  if (nk <= k[3]) return;
  k[3] = nk;
  if (k[3] > k[2]) { u32 t = k[2]; k[2] = k[3]; k[3] = t; }
  if (k[2] > k[1]) { u32 t = k[1]; k[1] = k[2]; k[2] = t; }
  if (k[1] > k[0]) { u32 t = k[0]; k[0] = k[1]; k[1] = t; }
}

// ---------------- fused f32->bf16 convert + embedding (one launch) ----------------
struct F2BArgs {
  const float* s[10];
  bf16_t* d[10];
  int n4[10];
  const int* ids;
  const float* pos;
  float* x;
  bf16_t* xb;
};
__global__ void k_f2b_all(F2BArgs a) {
  const int seg = blockIdx.y;
  if (seg == 10) {
    const int d = threadIdx.x * 2;
    for (int r = blockIdx.x; r < 4096; r += gridDim.x) {
      const int t = r & 2047;
      const long id = a.ids[r];
      float2 av = *(const float2*)(a.s[0] + id * 512 + d);
      float2 p = *(const float2*)(a.pos + (long)t * 512 + d);
      float o0 = av.x + p.x, o1 = av.y + p.y;
      *(float2*)(a.x + (long)r * 512 + d) = make_float2(o0, o1);
      bf16x2 ob = {(bf16_t)o0, (bf16_t)o1};
      *(bf16x2*)(a.xb + (long)r * 512 + d) = ob;
    }
    return;
  }
  const float* __restrict__ in = a.s[seg];
  bf16_t* __restrict__ out = a.d[seg];
  const long n4 = a.n4[seg];
  const long stride = (long)gridDim.x * blockDim.x;
  for (long i = (long)blockIdx.x * blockDim.x + threadIdx.x; i < n4; i += stride) {
    float4 v = ((const float4*)in)[i];
    bf16x4 o = {(bf16_t)v.x, (bf16_t)v.y, (bf16_t)v.z, (bf16_t)v.w};
    ((bf16x4*)out)[i] = o;
  }
}

DEVI float gelu_f(float f) {
  return 0.5f * f * (1.0f + erff(f * 0.70710678118654752f));
}

// ---------------- 128x128 GEMM, 3-slot counted-vmcnt pipeline (48KB LDS, 3 blk/CU) ----------------
// EPI: 0 plain store; 2 gelu->bf16; 3 score top-4 -> cand[M][224][4].
template <typename CT, bool BIAS, int EPI>
__global__ __launch_bounds__(256, 3) void k_gemm_bt(
    const bf16_t* __restrict__ A, int lda, const bf16_t* __restrict__ B, int ldb,
    CT* __restrict__ C, int ldc, const float* __restrict__ bias, int K, float alpha,
    const float* __restrict__ s0, const float* __restrict__ s1,
    const float* __restrict__ s2, u32* __restrict__ cand) {
  __shared__ bf16_t SH[24576];  // 48KB: A slots [0,12288), B slots [12288,24576)
  const int tid = threadIdx.x;
  const int lane = tid & 63;
  const int w = tid >> 6;
  const int wm = w >> 1, wn = w & 1;
  const int m0 = blockIdx.y * 128;
  const int n0 = blockIdx.x * 128;

  f32x4 acc[4][4];
#pragma unroll
  for (int m = 0; m < 4; ++m)
#pragma unroll
    for (int n = 0; n < 4; ++n) acc[m][n] = (f32x4){0.f, 0.f, 0.f, 0.f};

  const int srow = tid >> 2;
  const int scol = ((tid & 3) ^ ((srow >> 1) & 3)) * 8;  // pre-swizzled source granule
  const int fr = lane & 15;
  const int g4 = lane >> 4;
  const int kg = g4 * 8;
  const int NT = K >> 5;

  auto stage = [&](int kp) {
    const int slot = kp % 3;
    bf16_t* as = SH + slot * 4096;
    bf16_t* bs = SH + 12288 + slot * 4096;
    const int k0 = kp * 32;
    g2l16(A + (long long)(m0 + srow) * lda + (k0 + scol), as + tid * 8);
    g2l16(A + (long long)(m0 + 64 + srow) * lda + (k0 + scol), as + 2048 + tid * 8);
    g2l16(B + (long long)(n0 + srow) * ldb + (k0 + scol), bs + tid * 8);
    g2l16(B + (long long)(n0 + 64 + srow) * ldb + (k0 + scol), bs + 2048 + tid * 8);
  };

  stage(0);
  stage(1);
  asm volatile("s_waitcnt vmcnt(4)" ::: "memory");
  __builtin_amdgcn_s_barrier();
  __builtin_amdgcn_sched_barrier(0);

  for (int k = 0; k < NT; ++k) {
    const int slot = k % 3;
    const bf16_t* as = SH + slot * 4096;
    const bf16_t* bs = SH + 12288 + slot * 4096;
    bf16x8 fa[4], fb[4];
#pragma unroll
    for (int m = 0; m < 4; ++m) {
      const int row = wm * 64 + m * 16 + fr;
      fa[m] = *(const bf16x8*)(as + row * 32 + (kg ^ (((row >> 1) & 3) << 3)));
    }
#pragma unroll
    for (int n = 0; n < 4; ++n) {
      const int row = wn * 64 + n * 16 + fr;
      fb[n] = *(const bf16x8*)(bs + row * 32 + (kg ^ (((row >> 1) & 3) << 3)));
    }
    if (k + 2 < NT) stage(k + 2);
    if (k < NT - 2) {
      asm volatile("s_waitcnt vmcnt(4)" ::: "memory");
    } else {
      asm volatile("s_waitcnt vmcnt(0)" ::: "memory");
    }
    __builtin_amdgcn_s_barrier();
    __builtin_amdgcn_sched_barrier(0);
    __builtin_amdgcn_s_setprio(1);
#pragma unroll
    for (int m = 0; m < 4; ++m)
#pragma unroll
      for (int n = 0; n < 4; ++n)
        acc[m][n] = __builtin_amdgcn_mfma_f32_16x16x32_bf16(fa[m], fb[n], acc[m][n], 0, 0, 0);
    __builtin_amdgcn_s_setprio(0);
  }

  if (EPI == 3) {
    // ---- score epilogue: add salience, block-local per-row top-4 -> cand ----
    const float* salp;
    if (n0 < 16384) salp = s0 + n0;
    else if (n0 < 24576) salp = s1 + (n0 - 16384);
    else salp = s2 + (n0 - 24576);
    float bv[4];
    int coll[4];
#pragma unroll
    for (int n = 0; n < 4; ++n) {
      coll[n] = wn * 64 + n * 16 + fr;
      bv[n] = salp[coll[n]];
    }
    __syncthreads();
    u16* slab = (u16*)SH;  // [128 rows][128 cols] bf16, col idx XOR (row&7)<<3 (32KB)
    u32* res = (u32*)(SH + 16384);  // 128*2*4 u32 = 4KB
#pragma unroll
    for (int m = 0; m < 4; ++m) {
#pragma unroll
      for (int r = 0; r < 4; ++r) {
        const int rl = wm * 64 + m * 16 + g4 * 4 + r;
        const int sw = (rl & 7) << 3;
#pragma unroll
        for (int n = 0; n < 4; ++n) {
          bf16_t bvv = (bf16_t)(acc[m][n][r] + bv[n]);
          slab[rl * 128 + (coll[n] ^ sw)] = __builtin_bit_cast(u16, bvv);
        }
      }
    }
    __syncthreads();
    const int rr = tid & 127;
    const int hh = tid >> 7;
    const int sw = (rr & 7) << 3;
    u32 rk[4] = {0u, 0u, 0u, 0u};
    const u32 ibase = 0x7FFFu - (u32)n0;
#pragma unroll
    for (int j = 0; j < 8; ++j) {
      const int c0 = hh * 64 + j * 8;
      u16x8 vv = *(const u16x8*)(slab + rr * 128 + (c0 ^ sw));
#pragma unroll
      for (int e = 0; e < 8; ++e) {
        u16 sb = vv[e];
        u32 k16 = (u32)sb ^ (0x8000u | (0x7FFFu * (u32)(sb >> 15)));
        tki4(rk, (k16 << 15) | (ibase - (u32)(c0 + e)));
      }
    }
#pragma unroll
    for (int j = 0; j < 4; ++j) res[(rr * 2 + hh) * 4 + j] = rk[j];
    __syncthreads();
    if (tid < 128) {
      const u32* rp = res + tid * 8;
      u32 fin[4] = {rp[0], rp[1], rp[2], rp[3]};
      tki4(fin, rp[4]); tki4(fin, rp[5]); tki4(fin, rp[6]); tki4(fin, rp[7]);
      u32* cp = cand + ((long long)(m0 + tid) * 224 + (n0 >> 7)) * 4;
#pragma unroll
      for (int j = 0; j < 4; ++j) cp[j] = fin[j];
    }
    return;
  }

#pragma unroll
  for (int n = 0; n < 4; ++n) {
    const int col = n0 + wn * 64 + n * 16 + fr;
    const float bv = BIAS ? bias[col] : 0.0f;
#pragma unroll
    for (int m = 0; m < 4; ++m) {
      const long long rb = m0 + wm * 64 + m * 16 + g4 * 4;
#pragma unroll
      for (int r = 0; r < 4; ++r) {
        float v = (acc[m][n][r] + bv) * alpha;
        if (EPI == 2) v = gelu_f(v);
        C[(rb + r) * (long long)ldc + col] = (CT)v;
      }
    }
  }
}

// ---------------- 64x128 GEMM, K-split over z, 3-slot counted-vmcnt pipeline ----------------
// EPI: 0 plain store; 1 qkv split (q*0.125->qh, k->kh, v->vt); 2 gelu->bf16.
template <typename CT, bool BIAS, int EPI = 0>
__global__ __launch_bounds__(256, 4) void k_gemm64(
    const bf16_t* __restrict__ A, int lda, const bf16_t* __restrict__ B, int ldb,
    CT* __restrict__ C, int ldc, long long sCz, const float* __restrict__ bias,
    int K, float alpha, bf16_t* __restrict__ qh, bf16_t* __restrict__ kh,
    bf16_t* __restrict__ vt) {
  __shared__ bf16_t As[3][2048];  // slot x [64][32]
  __shared__ bf16_t Bs[3][4096];  // slot x [128][32]
  const int tid = threadIdx.x;
  const int lane = tid & 63;
  const int w = tid >> 6;
  const int wm = w >> 1, wn = w & 1;
  const int m0 = blockIdx.y * 64;
  const int n0 = blockIdx.x * 128;
  const int kz = blockIdx.z;
  A += (long long)kz * K;
  B += (long long)kz * K;
  C += (long long)kz * sCz;

  f32x4 acc[2][4];
#pragma unroll
  for (int m = 0; m < 2; ++m)
#pragma unroll
    for (int n = 0; n < 4; ++n) acc[m][n] = (f32x4){0.f, 0.f, 0.f, 0.f};

  const int srow = tid >> 2;
  const int scol = ((tid & 3) ^ ((srow >> 1) & 3)) * 8;  // pre-swizzled source granule
  const int fr = lane & 15;
  const int g4 = lane >> 4;
  const int kg = g4 * 8;
  const int NT = K >> 5;

  auto stage = [&](int kp) {
    const int slot = kp % 3;
    bf16_t* as = As[slot];
    bf16_t* bs = Bs[slot];
    const int k0 = kp * 32;
    g2l16(A + (long long)(m0 + srow) * lda + (k0 + scol), as + tid * 8);
    g2l16(B + (long long)(n0 + srow) * ldb + (k0 + scol), bs + tid * 8);
    g2l16(B + (long long)(n0 + 64 + srow) * ldb + (k0 + scol), bs + 2048 + tid * 8);
  };

  stage(0);
  stage(1);
  asm volatile("s_waitcnt vmcnt(3)" ::: "memory");
  __builtin_amdgcn_s_barrier();
  __builtin_amdgcn_sched_barrier(0);

  for (int k = 0; k < NT; ++k) {
    const int slot = k % 3;
    const bf16_t* as = As[slot];
    const bf16_t* bs = Bs[slot];
    bf16x8 fa[2], fb[4];
#pragma unroll
    for (int m = 0; m < 2; ++m) {
      const int row = wm * 32 + m * 16 + fr;
      fa[m] = *(const bf16x8*)(as + row * 32 + (kg ^ (((row >> 1) & 3) << 3)));
    }
#pragma unroll
    for (int n = 0; n < 4; ++n) {
      const int row = wn * 64 + n * 16 + fr;
      fb[n] = *(const bf16x8*)(bs + row * 32 + (kg ^ (((row >> 1) & 3) << 3)));
    }
    if (k + 2 < NT) stage(k + 2);
    if (k < NT - 2) {
      asm volatile("s_waitcnt vmcnt(3)" ::: "memory");
    } else {
      asm volatile("s_waitcnt vmcnt(0)" ::: "memory");
    }
    __builtin_amdgcn_s_barrier();
    __builtin_amdgcn_sched_barrier(0);
    __builtin_amdgcn_s_setprio(1);
#pragma unroll
    for (int m = 0; m < 2; ++m)
#pragma unroll
      for (int n = 0; n < 4; ++n)
        acc[m][n] = __builtin_amdgcn_mfma_f32_16x16x32_bf16(fa[m], fb[n], acc[m][n], 0, 0, 0);
    __builtin_amdgcn_s_setprio(0);
  }

#pragma unroll
  for (int n = 0; n < 4; ++n) {
    const int col = n0 + wn * 64 + n * 16 + fr;
    const float bv = (BIAS && kz == 0) ? bias[col] : 0.0f;
    if (EPI == 1) {
      const int reg = col >> 9;
      const int h = (col >> 6) & 7;
      const int hd = col & 63;
#pragma unroll
      for (int m = 0; m < 2; ++m) {
        const int rb = m0 + wm * 32 + m * 16 + g4 * 4;
#pragma unroll
        for (int r = 0; r < 4; ++r) {
          const int row = rb + r;
          const int b = row >> 11, t = row & 2047;
          const long long bh = (long long)b * 8 + h;
          float v = acc[m][n][r] + bv;
          if (reg == 0) qh[(bh * 2048 + t) * 64 + hd] = (bf16_t)(v * 0.125f);
          else if (reg == 1) kh[(bh * 2048 + t) * 64 + hd] = (bf16_t)v;
          else vt[(bh * 64 + hd) * 2048 + t] = (bf16_t)v;
        }
      }
    } else {
#pragma unroll
      for (int m = 0; m < 2; ++m) {
        const long long rb = m0 + wm * 32 + m * 16 + g4 * 4;
#pragma unroll
        for (int r = 0; r < 4; ++r) {
          float v = (acc[m][n][r] + bv) * alpha;
          if (EPI == 2) v = gelu_f(v);
          C[(rb + r) * (long long)ldc + col] = (CT)v;
        }
      }
    }
  }
}

// ---------------- fused flash attention (QBLK=64, KVBLK=128, 512 blocks = 2/CU) ----------------
__global__ __launch_bounds__(256, 2) void k_flash(
    const bf16_t* __restrict__ qh, const bf16_t* __restrict__ kh,
    const bf16_t* __restrict__ vt, bf16_t* __restrict__ out) {
  __shared__ bf16_t Ks[2][128 * 64];
  __shared__ bf16_t Vs[2][64 * 128];
  __shared__ bf16_t Ps[4 * 16 * 128];
  const int tid = threadIdx.x;
  const int lane = tid & 63;
  const int w = tid >> 6;
  const int bh = blockIdx.y;
  const int q0 = blockIdx.x * 64;
  const int fr = lane & 15;
  const int g4 = lane >> 4;
  const int kg = g4 * 8;

  bf16x8 qf[2];
  {
    const bf16_t* qb = qh + ((long long)bh * 2048 + q0 + w * 16) * 64;
#pragma unroll
    for (int ks = 0; ks < 2; ++ks)
      qf[ks] = *(const bf16x8*)(qb + fr * 64 + ks * 32 + kg);
  }

  f32x4 oacc[4];
#pragma unroll
  for (int n = 0; n < 4; ++n) oacc[n] = (f32x4){0.f, 0.f, 0.f, 0.f};
  float li[4] = {0.f, 0.f, 0.f, 0.f};

  char* PsW = (char*)(Ps + w * 16 * 128);
  const bf16_t* kbase = kh + (long long)bh * 2048 * 64;
  const bf16_t* vbase = vt + (long long)bh * 64 * 2048;

  auto stage = [&](int kt, int buf) {
#pragma unroll
    for (int i = 0; i < 4; ++i) {
      int row = (w * 4 + i) * 8 + (lane >> 3);
      int c = lane & 7;
      g2l16(kbase + ((long long)(kt * 128 + row)) * 64 + (c ^ (row & 7)) * 8,
            Ks[buf] + (w * 4 + i) * 512);
      int d = w * 16 + i * 4 + (lane >> 4);
      int c2 = lane & 15;
      g2l16(vbase + (long long)d * 2048 + kt * 128 + ((c2 ^ (d & 7)) * 8),
            Vs[buf] + (w * 16 + i * 4) * 128);
    }
  };

  stage(0, 0);
  int buf = 0;
  for (int kt = 0; kt < 16; ++kt) {
    __syncthreads();
    if (kt + 1 < 16) stage(kt + 1, buf ^ 1);

    f32x4 s[8];
#pragma unroll
    for (int n = 0; n < 8; ++n) s[n] = (f32x4){0.f, 0.f, 0.f, 0.f};
#pragma unroll
    for (int ks = 0; ks < 2; ++ks) {
#pragma unroll
      for (int n = 0; n < 8; ++n) {
        int row = n * 16 + fr;
        bf16x8 kf = *(const bf16x8*)((const char*)Ks[buf] + row * 128 +
                                     ((ks * 64 + kg * 2) ^ ((row & 7) << 4)));
        s[n] = __builtin_amdgcn_mfma_f32_16x16x32_bf16(qf[ks], kf, s[n], 0, 0, 0);
      }
    }

#pragma unroll
    for (int r = 0; r < 4; ++r) {
      const int lr = g4 * 4 + r;
      const int sw = (lr & 7) << 4;
      float rs = 0.f;
#pragma unroll
      for (int n = 0; n < 8; ++n) {
        float p = __expf(s[n][r]);
        rs += p;
        *(bf16_t*)(PsW + lr * 256 + (((n * 16 + fr) * 2) ^ sw)) = (bf16_t)p;
      }
      li[r] += rs;
    }

#pragma unroll
    for (int ks = 0; ks < 4; ++ks) {
      bf16x8 pa = *(const bf16x8*)(PsW + fr * 256 +
                                   ((ks * 64 + kg * 2) ^ ((fr & 7) << 4)));
#pragma unroll
      for (int n = 0; n < 4; ++n) {
        int d = n * 16 + fr;
        bf16x8 vf = *(const bf16x8*)((const char*)Vs[buf] + d * 256 +
                                     ((ks * 64 + kg * 2) ^ ((d & 7) << 4)));
        oacc[n] = __builtin_amdgcn_mfma_f32_16x16x32_bf16(pa, vf, oacc[n], 0, 0, 0);
      }
    }
    buf ^= 1;
  }

#pragma unroll
  for (int r = 0; r < 4; ++r) {
    li[r] += __shfl_xor(li[r], 1);
    li[r] += __shfl_xor(li[r], 2);
    li[r] += __shfl_xor(li[r], 4);
    li[r] += __shfl_xor(li[r], 8);
  }

  const int b = bh >> 3, h = bh & 7;
  bf16_t* ob = out + ((long long)b * 2048 + q0 + w * 16) * 512 + h * 64;
#pragma unroll
  for (int r = 0; r < 4; ++r) {
    float inv = 1.0f / li[r];
#pragma unroll
    for (int n = 0; n < 4; ++n)
      ob[(g4 * 4 + r) * 512 + n * 16 + fr] = (bf16_t)(oacc[n][r] * inv);
  }
}

// ---------------- LN(xin + d1 + d2) * s + b -> xout (f32) + xbf (bf16), D=512 ----------------
// d1/d2 are bf16 K-split partials.
__global__ void k_ln2(const float* __restrict__ xin, const bf16_t* __restrict__ d1,
                      const bf16_t* __restrict__ d2, const float* __restrict__ s,
                      const float* __restrict__ b, float* __restrict__ xout,
                      bf16_t* __restrict__ xbf) {
  __shared__ float red[8];
  const int r = blockIdx.x;
  const int tid = threadIdx.x;
  const int d = tid * 2;
  const int lane = tid & 63, w = tid >> 6;
  float2 xi = *(const float2*)(xin + (long)r * 512 + d);
  bf16x2 e1 = *(const bf16x2*)(d1 + (long)r * 512 + d);
  bf16x2 e2 = *(const bf16x2*)(d2 + (long)r * 512 + d);
  float y0 = xi.x + (float)e1[0] + (float)e2[0];
  float y1 = xi.y + (float)e1[1] + (float)e2[1];
  float sum = y0 + y1, ss = y0 * y0 + y1 * y1;
#pragma unroll
  for (int o = 32; o > 0; o >>= 1) { sum += __shfl_xor(sum, o); ss += __shfl_xor(ss, o); }
  if (lane == 0) { red[w] = sum; red[4 + w] = ss; }
  __syncthreads();
  sum = red[0] + red[1] + red[2] + red[3];
  ss = red[4] + red[5] + red[6] + red[7];
  const float mean = sum * (1.0f / 512.0f);
  const float var = ss * (1.0f / 512.0f) - mean * mean;
  const float rstd = rsqrtf(var + 1e-5f);
  float o0 = (y0 - mean) * rstd * s[d] + b[d];
  float o1 = (y1 - mean) * rstd * s[d + 1] + b[d + 1];
  if (xout) *(float2*)(xout + (long)r * 512 + d) = make_float2(o0, o1);
  bf16x2 ob = {(bf16_t)o0, (bf16_t)o1};
  *(bf16x2*)(xbf + (long)r * 512 + d) = ob;
}

// ---------------- fused: merge candidates (waves 0-2, one level each) + gather V ----------------
__global__ void k_topkread(const u32* __restrict__ cand, const float* __restrict__ V0,
                           const float* __restrict__ V1, const float* __restrict__ V2,
                           bf16_t* __restrict__ readb) {
  __shared__ float tvS[3][4];
  __shared__ int tiS[3][4];
  const int r = blockIdx.x;
  const int lane = threadIdx.x & 63;
  const int w = threadIdx.x >> 6;
  if (w < 3) {
    const int cnt = w == 0 ? 128 : (w == 1 ? 64 : 32);
    const int base = w == 0 ? 0 : (w == 1 ? 128 : 192);
    const int coff = w == 0 ? 0 : (w == 1 ? 16384 : 24576);
    const u32* cr = cand + (long long)r * 224 + base;
    u32 rk[4] = {0u, 0u, 0u, 0u};
    for (int j = lane; j < cnt; j += 64) tki4(rk, cr[j]);
#pragma unroll
    for (int dd = 1; dd < 64; dd <<= 1) {
      u32 o[4];
#pragma unroll
      for (int j = 0; j < 4; ++j) o[j] = (u32)__shfl_xor((int)rk[j], dd);
#pragma unroll
      for (int j = 0; j < 4; ++j) tki4(rk, o[j]);
    }
    if (lane == 0) {
#pragma unroll
      for (int j = 0; j < 4; ++j) {
        u32 k16 = rk[j] >> 15;
        u16 b = (k16 & 0x8000u) ? (u16)(k16 ^ 0x8000u) : (u16)(~k16);
        u32 fb = ((u32)b) << 16;
        tvS[w][j] = __uint_as_float(fb);
        tiS[w][j] = (0x7FFF - (int)(rk[j] & 0x7FFF)) - coff;
      }
    }
  }
  __syncthreads();
  const int d = threadIdx.x * 2;
  float a0 = 0.f, a1 = 0.f;
  const float* Vs[3] = {V0, V1, V2};
  const int smax[3] = {16383, 8191, 4095};
#pragma unroll
  for (int lev = 0; lev < 3; ++lev) {
    float t0 = tvS[lev][0], t1 = tvS[lev][1], t2 = tvS[lev][2], t3 = tvS[lev][3];
    float m = fmaxf(fmaxf(t0, t1), fmaxf(t2, t3));
    float e0 = __expf(t0 - m), e1 = __expf(t1 - m), e2 = __expf(t2 - m), e3 = __expf(t3 - m);
    float inv = 1.0f / (e0 + e1 + e2 + e3);
    float w4[4] = {e0 * inv, e1 * inv, e2 * inv, e3 * inv};
#pragma unroll
    for (int k = 0; k < 4; ++k) {
      int idx = tiS[lev][k];
      idx = idx < 0 ? 0 : (idx > smax[lev] ? smax[lev] : idx);  // safety clamp
      const float* vr = Vs[lev] + (long)idx * 512;
      a0 += w4[k] * vr[d];
      a1 += w4[k] * vr[d + 1];
    }
  }
  bf16x2 o = {(bf16_t)(a0 * (1.0f / 3.0f)), (bf16_t)(a1 * (1.0f / 3.0f))};
  *(bf16x2*)(readb + (long)r * 512 + d) = o;
}

// ---------------- host ----------------
extern "C" void kernel_launch(void* const* d_in, const int* in_sizes, int n_in,
                              void* d_out, int out_size, void* d_ws, size_t ws_size,
                              hipStream_t stream) {
  (void)in_sizes; (void)n_in; (void)out_size; (void)ws_size;
  const int* ids = (const int*)d_in[0];
  const float* tok = (const float*)d_in[1];
  const float* pos = (const float*)d_in[2];
  const float* Wqkv = (const float*)d_in[3];
  const float* bqkv = (const float*)d_in[4];
  const float* Wo = (const float*)d_in[5];
  const float* bo = (const float*)d_in[6];
  const float* ln1s = (const float*)d_in[7];
  const float* ln1b = (const float*)d_in[8];
  const float* W1 = (const float*)d_in[9];
  const float* b1 = (const float*)d_in[10];
  const float* W2 = (const float*)d_in[11];
  const float* b2 = (const float*)d_in[12];
  const float* ln2s = (const float*)d_in[13];
  const float* ln2b = (const float*)d_in[14];
  const float* Wq = (const float*)d_in[15];
  const float* bq = (const float*)d_in[16];
  const float* Wrp = (const float*)d_in[17];
  const float* brp = (const float*)d_in[18];
  const float* lnos = (const float*)d_in[19];
  const float* lnob = (const float*)d_in[20];
  const float* K0 = (const float*)d_in[21];
  const float* V0 = (const float*)d_in[22];
  const float* s0 = (const float*)d_in[23];
  const float* K1 = (const float*)d_in[24];
  const float* V1 = (const float*)d_in[25];
  const float* s1 = (const float*)d_in[26];
  const float* K2 = (const float*)d_in[27];
  const float* V2 = (const float*)d_in[28];
  const float* s2 = (const float*)d_in[29];

  char* wp = (char*)d_ws;
  auto walloc = [&](size_t bytes) -> char* {
    char* p = wp; wp += (bytes + 255) & ~(size_t)255; return p;
  };
  char* op = (char*)d_out;
  auto oalloc = [&](size_t bytes) -> char* {
    char* p = op; op += (bytes + 255) & ~(size_t)255; return p;
  };

  // transients in d_out (all reads complete before lm_head overwrites d_out)
  bf16_t* Wqkvb = (bf16_t*)oalloc(3145728ULL * 2);
  bf16_t* Wob   = (bf16_t*)oalloc(1048576ULL * 2);
  bf16_t* W1b   = (bf16_t*)oalloc(4194304ULL * 2);
  bf16_t* W2b   = (bf16_t*)oalloc(4194304ULL * 2);
  bf16_t* Wqb   = (bf16_t*)oalloc(262144ULL * 2);
  bf16_t* Wrpb  = (bf16_t*)oalloc(262144ULL * 2);
  bf16_t* Kb    = (bf16_t*)oalloc(28672ULL * 512 * 2);
  bf16_t* hb    = (bf16_t*)oalloc(4096ULL * 2048 * 2);
  u32*    cand  = (u32*)oalloc(4096ULL * 224 * 4 * 4);
  bf16_t* delta = (bf16_t*)oalloc(2ULL * 4096 * 512 * 2);  // 2 bf16 K-split partials

  // survivors in d_ws
  bf16_t* tokb = (bf16_t*)walloc(16384000ULL * 2);
  float*  x    = (float*)walloc(4096ULL * 512 * 4);
  bf16_t* xb   = (bf16_t*)walloc(4096ULL * 512 * 2);
  bf16_t* qh   = (bf16_t*)walloc(2097152ULL * 2);
  bf16_t* kh   = (bf16_t*)walloc(2097152ULL * 2);
  bf16_t* vt   = (bf16_t*)walloc(2097152ULL * 2);
  bf16_t* attob = (bf16_t*)walloc(4096ULL * 512 * 2);
  bf16_t* qmb  = (bf16_t*)walloc(4096ULL * 512 * 2);
  bf16_t* readb = (bf16_t*)walloc(4096ULL * 512 * 2);
  bf16_t* xfb  = (bf16_t*)walloc(4096ULL * 512 * 2);

  // all f32->bf16 conversions + embedding in one launch
  F2BArgs fa;
  fa.s[0] = tok;  fa.d[0] = tokb;  fa.n4[0] = 4096000;
  fa.s[1] = Wqkv; fa.d[1] = Wqkvb; fa.n4[1] = 786432;
  fa.s[2] = Wo;   fa.d[2] = Wob;   fa.n4[2] = 262144;
  fa.s[3] = W1;   fa.d[3] = W1b;   fa.n4[3] = 1048576;
  fa.s[4] = W2;   fa.d[4] = W2b;   fa.n4[4] = 1048576;
  fa.s[5] = Wq;   fa.d[5] = Wqb;   fa.n4[5] = 65536;
  fa.s[6] = Wrp;  fa.d[6] = Wrpb;  fa.n4[6] = 65536;
  fa.s[7] = K0;   fa.d[7] = Kb;                fa.n4[7] = 2097152;
  fa.s[8] = K1;   fa.d[8] = Kb + 8388608L;     fa.n4[8] = 1048576;
  fa.s[9] = K2;   fa.d[9] = Kb + 12582912L;    fa.n4[9] = 524288;
  fa.ids = ids; fa.pos = pos; fa.x = x; fa.xb = xb;
  k_f2b_all<<<dim3(128, 11), 256, 0, stream>>>(fa);

  const long long sCz = 4096LL * 512;
  for (int i = 0; i < 4; ++i) {
    // QKV GEMM (64-row tiles, 768 blocks = 3/CU) with fused split epilogue
    k_gemm64<bf16_t, true, 1><<<dim3(12, 64, 1), 256, 0, stream>>>(
        xb, 512, Wqkvb + (long long)i * 786432, 512, (bf16_t*)nullptr, 0, 0LL,
        bqkv + i * 1536, 512, 1.0f, qh, kh, vt);
    k_flash<<<dim3(32, 16), 256, 0, stream>>>(qh, kh, vt, attob);
    // Wo GEMM K-split (2 x K=256) -> bf16 delta partials
    k_gemm64<bf16_t, true><<<dim3(4, 64, 2), 256, 0, stream>>>(
        attob, 512, Wob + (long long)i * 262144, 512, delta, 512, sCz,
        bo + i * 512, 256, 1.0f, nullptr, nullptr, nullptr);
    k_ln2<<<4096, 256, 0, stream>>>(x, delta, delta + sCz,
                                    ln1s + i * 512, ln1b + i * 512, x, xb);
    // W1 GEMM + gelu (64-row tiles, 1024 blocks = 4/CU)
    k_gemm64<bf16_t, true, 2><<<dim3(16, 64, 1), 256, 0, stream>>>(
        xb, 512, W1b + (long long)i * 1048576, 512, hb, 2048, 0LL,
        b1 + i * 2048, 512, 1.0f, nullptr, nullptr, nullptr);
    // W2 GEMM K-split (2 x K=1024) -> bf16 delta partials
    k_gemm64<bf16_t, true><<<dim3(4, 64, 2), 256, 0, stream>>>(
        hb, 2048, W2b + (long long)i * 1048576, 2048, delta, 512, sCz,
        b2 + i * 512, 1024, 1.0f, nullptr, nullptr, nullptr);
    k_ln2<<<4096, 256, 0, stream>>>(x, delta, delta + sCz,
                                    ln2s + i * 512, ln2b + i * 512, x, xb);
  }

  // memory path: qm = (x@Wq^T + bq)/sqrt(512) in bf16
  k_gemm64<bf16_t, true><<<dim3(4, 64, 1), 256, 0, stream>>>(
      xb, 512, Wqb, 512, qmb, 512, 0LL, bq, 512, 0.044194173824159216f,
      nullptr, nullptr, nullptr);
  // score GEMM over concatenated banks, fused salience + per-block top-4 -> cand
  k_gemm_bt<bf16_t, false, 3><<<dim3(224, 32), 256, 0, stream>>>(
      qmb, 512, Kb, 512, (bf16_t*)nullptr, 0, nullptr, 512, 1.0f, s0, s1, s2, cand);
  // merge candidates + gather V in one launch
  k_topkread<<<4096, 256, 0, stream>>>(cand, V0, V1, V2, readb);
  // Wrp GEMM K-split + final LN
  k_gemm64<bf16_t, true><<<dim3(4, 64, 2), 256, 0, stream>>>(
      readb, 512, Wrpb, 512, delta, 512, sCz, brp, 256, 1.0f,
      nullptr, nullptr, nullptr);
  k_ln2<<<4096, 256, 0, stream>>>(x, delta, delta + sCz, lnos, lnob, nullptr, xfb);
  // logits = x @ tok_embed^T  (f32, overwrites all d_out scratch)
  k_gemm_bt<float, false, 0><<<dim3(250, 32), 256, 0, stream>>>(
      xfb, 512, tokb, 512, (float*)d_out, 32000, nullptr, 512, 1.0f,
      nullptr, nullptr, nullptr, nullptr);
}